// Round 4
// baseline (1960.635 us; speedup 1.0000x reference)
//
#include <hip/hip_runtime.h>

// G4GCN: 4-layer linear bipartite GNN (clauses <-> variables), feature dim 2.
//
// Round-3 lesson: layer kernels were bound by LDS atomics (~36M lane-atomics /
// kernel at ~0.3 lanes/cy/CU; all other pipes <5%). Round-4: finish the
// counting sort at build time -> full CSR per view (srcs sorted by target,
// rp offsets). Layer kernels = one thread per node, register accumulation,
// no LDS, no atomics. Counts come free from rp deltas.
//
// Paths by ws_size: full CSR (~180MB) -> bucket-LDS round-3 path (~132MB)
// -> global-atomic path (~56MB).

#define GAB 256  // blocks for build hist/scatter passes

static inline int cdiv_h(long long a, long long b) { return (int)((a + b - 1) / b); }

__device__ inline float bf_lo(unsigned u) { return __uint_as_float(u << 16); }
__device__ inline float bf_hi(unsigned u) { return __uint_as_float(u & 0xffff0000u); }
__device__ inline unsigned packy(float a, float b) {
    unsigned ua = __float_as_uint(a), ub = __float_as_uint(b);
    ua = (ua + 0x7fffu + ((ua >> 16) & 1u)) >> 16;
    ub = (ub + 0x7fffu + ((ub >> 16) & 1u)) & 0xffff0000u;
    return ua | ub;
}

// ---------------- build: bucket passes ----------------

__global__ void hist_kernel(const int* __restrict__ key, int e, int chunk, int shift,
                            int nb, unsigned* __restrict__ hist /*[nb][GAB]*/) {
    extern __shared__ unsigned h[];
    int blk = blockIdx.x, tid = threadIdx.x;
    for (int i = tid; i < nb; i += blockDim.x) h[i] = 0u;
    __syncthreads();
    int s = blk * chunk, epos = min(e, s + chunk);
    for (int i = s + tid; i < epos; i += blockDim.x)
        atomicAdd(&h[key[i] >> shift], 1u);
    __syncthreads();
    for (int i = tid; i < nb; i += blockDim.x) hist[(size_t)i * GAB + blk] = h[i];
}

__global__ void rowscan256(const unsigned* __restrict__ hist, unsigned* __restrict__ rowscan,
                           unsigned* __restrict__ row_total) {
    __shared__ unsigned ts[256];
    int b = blockIdx.x, t = threadIdx.x;
    unsigned v0 = hist[(size_t)b * GAB + t];
    ts[t] = v0;
    __syncthreads();
    for (int off = 1; off < 256; off <<= 1) {
        unsigned v = (t >= off) ? ts[t - off] : 0u;
        __syncthreads();
        ts[t] += v;
        __syncthreads();
    }
    rowscan[(size_t)b * GAB + t] = ts[t] - v0;
    if (t == 255) row_total[b] = ts[255];
}

__global__ void basescan_kernel(const unsigned* __restrict__ row_total,
                                unsigned* __restrict__ base, int nb) {
    __shared__ unsigned a[2048];
    __shared__ unsigned ts[1024];
    int t = threadIdx.x;
    a[t] = (t < nb) ? row_total[t] : 0u;
    a[t + 1024] = (t + 1024 < nb) ? row_total[t + 1024] : 0u;
    __syncthreads();
    unsigned a0 = a[2 * t], a1 = a[2 * t + 1];
    unsigned sum = a0 + a1;
    ts[t] = sum;
    __syncthreads();
    for (int off = 1; off < 1024; off <<= 1) {
        unsigned v = (t >= off) ? ts[t - off] : 0u;
        __syncthreads();
        ts[t] += v;
        __syncthreads();
    }
    unsigned b0 = ts[t] - sum;
    if (2 * t <= nb) base[2 * t] = b0;
    if (2 * t + 1 <= nb) base[2 * t + 1] = b0 + a0;
}

// edge lists -> bucketed entries: entry = (payload << shift) | (key & mask)
__global__ void scatter_kernel(const int* __restrict__ key, const int* __restrict__ payload,
                               int e, int chunk, int shift, int mask, int nb,
                               const unsigned* __restrict__ rowscan,
                               const unsigned* __restrict__ base,
                               unsigned* __restrict__ out) {
    extern __shared__ unsigned cur[];
    int blk = blockIdx.x, tid = threadIdx.x;
    for (int i = tid; i < nb; i += blockDim.x)
        cur[i] = base[i] + rowscan[(size_t)i * GAB + blk];
    __syncthreads();
    int s = blk * chunk, epos = min(e, s + chunk);
    for (int i = s + tid; i < epos; i += blockDim.x) {
        int k = key[i];
        int b = k >> shift;
        unsigned p = atomicAdd(&cur[b], 1u);
        out[p] = ((unsigned)payload[i] << shift) | (unsigned)(k & mask);
    }
}

// per-bucket local counting sort -> global CSR (srcs sorted by target, rp offsets)
template <int BW>
__global__ __launch_bounds__(256) void localsort_kernel(
    const unsigned* __restrict__ ent, const unsigned* __restrict__ base,
    int nb, int n, int shift, unsigned* __restrict__ srcs, unsigned* __restrict__ rp) {
    constexpr int R = BW / 256;
    __shared__ unsigned h[BW];
    __shared__ unsigned ts[256];
    int b = blockIdx.x, t = threadIdx.x;
    unsigned s = base[b], eend = base[b + 1];
    for (int k = 0; k < R; ++k) h[t * R + k] = 0u;
    __syncthreads();
    for (unsigned i = s + t; i < eend; i += 256)
        atomicAdd(&h[ent[i] & (BW - 1)], 1u);
    __syncthreads();
    unsigned v0[R];
    unsigned sum = 0;
    for (int k = 0; k < R; ++k) { v0[k] = h[t * R + k]; sum += v0[k]; }
    ts[t] = sum;
    __syncthreads();
    for (int off = 1; off < 256; off <<= 1) {
        unsigned x = (t >= off) ? ts[t - off] : 0u;
        __syncthreads();
        ts[t] += x;
        __syncthreads();
    }
    unsigned ex = ts[t] - sum;
    for (int k = 0; k < R; ++k) { h[t * R + k] = ex; ex += v0[k]; }
    __syncthreads();
    for (int k = 0; k < R; ++k) {
        int idx = b * BW + t * R + k;
        if (idx < n) rp[idx] = s + h[t * R + k];
    }
    if (b == nb - 1 && t == 0) rp[n] = eend;
    __syncthreads();
    for (unsigned i = s + t; i < eend; i += 256) {
        unsigned u = ent[i];
        unsigned p = s + atomicAdd(&h[u & (BW - 1)], 1u);
        srcs[p] = u >> shift;
    }
}

// ---------------- node init ----------------

__global__ void init_c_kernel(const float* __restrict__ x, const float* __restrict__ deg,
                              const float* __restrict__ W0, const float* __restrict__ b0,
                              float2* __restrict__ xc, unsigned* __restrict__ yc, int n) {
    int i = blockIdx.x * blockDim.x + threadIdx.x;
    if (i >= n) return;
    float xi = x[i];
    float2 o = make_float2(fmaf(xi, W0[0], b0[0]), fmaf(xi, W0[1], b0[1]));
    xc[i] = o;
    float d = deg[i];
    float inv = (d > 0.f) ? rsqrtf(d) : 0.f;
    yc[i] = packy(inv * o.x, inv * o.y);
}

__global__ void init_v_kernel(const float* __restrict__ x, const float* __restrict__ deg,
                              const float* __restrict__ W0, const float* __restrict__ b0,
                              float2* __restrict__ xv, unsigned* __restrict__ yv, int n) {
    int i = blockIdx.x * blockDim.x + threadIdx.x;
    if (i >= n) return;
    float xi = x[i];
    float2 o = make_float2(fmaf(xi, W0[0], b0[0]), fmaf(xi, W0[1], b0[1]));
    xv[i] = o;
    float d = deg[i];
    float inv = (d > 0.f) ? rsqrtf(d) : 0.f;
    yv[i] = packy(inv * o.x, inv * o.y);
}

// ---------------- CSR layer kernels (no LDS, no atomics) ----------------

__global__ __launch_bounds__(256) void v_layer_csr(
    const unsigned* __restrict__ rp_p, const unsigned* __restrict__ src_p,
    const unsigned* __restrict__ rp_n, const unsigned* __restrict__ src_n,
    const unsigned* __restrict__ yc, const float2* __restrict__ xv_in,
    const float* __restrict__ deg_v, const float* __restrict__ W,
    const float* __restrict__ bias, float2* __restrict__ xv_out,
    unsigned* __restrict__ yv_out, int nv, int writeY) {
    int i = blockIdx.x * blockDim.x + threadIdx.x;
    if (i >= nv) return;
    unsigned s0 = rp_p[i], e0 = rp_p[i + 1];
    unsigned s1 = rp_n[i], e1 = rp_n[i + 1];
    float ax = 0.f, ay = 0.f, bx = 0.f, by = 0.f;
    for (unsigned j = s0; j < e0; ++j) {
        unsigned yw = yc[src_p[j]];
        ax += bf_lo(yw); ay += bf_hi(yw);
    }
    for (unsigned j = s1; j < e1; ++j) {
        unsigned yw = yc[src_n[j]];
        bx += bf_lo(yw); by += bf_hi(yw);
    }
    float cp = (float)(e0 - s0), cn = (float)(e1 - s1);
    float2 xi = xv_in[i];
    float dv = deg_v[i];
    float iv = (dv > 0.f) ? rsqrtf(dv) : 0.f;
    float m0 = fmaf(iv, ax, cp * xi.x);
    float m1 = fmaf(iv, ay, cp * xi.y);
    float m2 = fmaf(iv, bx, cn * xi.x);
    float m3 = fmaf(iv, by, cn * xi.y);
    float o0 = bias[0] + m0 * W[0] + m1 * W[2] + m2 * W[4] + m3 * W[6] + xi.x * W[8] + xi.y * W[10];
    float o1 = bias[1] + m0 * W[1] + m1 * W[3] + m2 * W[5] + m3 * W[7] + xi.x * W[9] + xi.y * W[11];
    xv_out[i] = make_float2(o0, o1);
    if (writeY) yv_out[i] = packy(iv * o0, iv * o1);
}

__global__ __launch_bounds__(256) void c_layer_csr(
    const unsigned* __restrict__ rp_p, const unsigned* __restrict__ src_p,
    const unsigned* __restrict__ rp_n, const unsigned* __restrict__ src_n,
    const unsigned* __restrict__ yv, float2* __restrict__ xc,
    const float* __restrict__ deg_c, unsigned* __restrict__ yc,
    const float* __restrict__ W, const float* __restrict__ bias, int nc) {
    int i = blockIdx.x * blockDim.x + threadIdx.x;
    if (i >= nc) return;
    unsigned s0 = rp_p[i], e0 = rp_p[i + 1];
    unsigned s1 = rp_n[i], e1 = rp_n[i + 1];
    float ax = 0.f, ay = 0.f, bx = 0.f, by = 0.f;
    for (unsigned j = s0; j < e0; ++j) {
        unsigned yw = yv[src_p[j]];
        ax += bf_lo(yw); ay += bf_hi(yw);
    }
    for (unsigned j = s1; j < e1; ++j) {
        unsigned yw = yv[src_n[j]];
        bx += bf_lo(yw); by += bf_hi(yw);
    }
    float cp = (float)(e0 - s0), cn = (float)(e1 - s1);
    float2 xi = xc[i];
    float dc = deg_c[i];
    float ic = (dc > 0.f) ? rsqrtf(dc) : 0.f;
    float m0 = fmaf(ic, ax, cp * xi.x);
    float m1 = fmaf(ic, ay, cp * xi.y);
    float m2 = fmaf(ic, bx, cn * xi.x);
    float m3 = fmaf(ic, by, cn * xi.y);
    float o0 = bias[0] + m0 * W[0] + m1 * W[2] + m2 * W[4] + m3 * W[6] + xi.x * W[8] + xi.y * W[10];
    float o1 = bias[1] + m0 * W[1] + m1 * W[3] + m2 * W[5] + m3 * W[7] + xi.x * W[9] + xi.y * W[11];
    xc[i] = make_float2(o0, o1);
    yc[i] = packy(ic * o0, ic * o1);
}

// ---------------- fallback A: round-3 bucket-LDS path ----------------

__global__ __launch_bounds__(256) void vscatter_kernel(
    const unsigned* __restrict__ cview, int e, int chunk, int nbc,
    const unsigned* __restrict__ base_c, const unsigned* __restrict__ rowscan_v,
    const unsigned* __restrict__ base_v, int nbv, unsigned* __restrict__ out) {
    extern __shared__ unsigned sm[];
    unsigned* cur = sm;
    unsigned* bc = sm + nbv;
    int blk = blockIdx.x, tid = threadIdx.x;
    for (int i = tid; i < nbv; i += 256)
        cur[i] = base_v[i] + rowscan_v[(size_t)i * GAB + blk];
    for (int i = tid; i <= nbc; i += 256) bc[i] = base_c[i];
    __syncthreads();
    int s = blk * chunk, epos = min(e, s + chunk);
    int i = s + tid;
    if (i < epos) {
        int lo = 0, hi = nbc;
        while (lo + 1 < hi) {
            int mid = (lo + hi) >> 1;
            if (bc[mid] <= (unsigned)i) lo = mid; else hi = mid;
        }
        int cb = lo;
        for (; i < epos; i += 256) {
            while ((unsigned)i >= bc[cb + 1]) ++cb;
            unsigned u = cview[i];
            unsigned v = u >> 10;
            unsigned c = ((unsigned)cb << 10) | (u & 1023u);
            unsigned p = atomicAdd(&cur[v >> 8], 1u);
            out[p] = (c << 8) | (v & 255u);
        }
    }
}

__global__ __launch_bounds__(256) void v_layer_kernel(
    const unsigned* __restrict__ bkt_pos, const unsigned* __restrict__ base_pos,
    const unsigned* __restrict__ bkt_neg, const unsigned* __restrict__ base_neg,
    const unsigned* __restrict__ yc, const float2* __restrict__ xv_in,
    const float* __restrict__ deg_v, const float* __restrict__ W,
    const float* __restrict__ bias, float2* __restrict__ xv_out,
    unsigned* __restrict__ yv_out, int nv, int writeY) {
    __shared__ float sx[2][256], sy[2][256], cnt[2][256];
    int b = blockIdx.x, t = threadIdx.x;
    sx[0][t] = 0.f; sx[1][t] = 0.f; sy[0][t] = 0.f; sy[1][t] = 0.f;
    cnt[0][t] = 0.f; cnt[1][t] = 0.f;
    __syncthreads();
    for (int pol = 0; pol < 2; ++pol) {
        const unsigned* bkt = pol ? bkt_neg : bkt_pos;
        const unsigned* bse = pol ? base_neg : base_pos;
        unsigned s = bse[b], epos = bse[b + 1];
        for (unsigned i = s + t; i < epos; i += 256) {
            unsigned u = bkt[i];
            unsigned c = u >> 8;
            int loc = (int)(u & 255u);
            unsigned yw = yc[c];
            atomicAdd(&sx[pol][loc], bf_lo(yw));
            atomicAdd(&sy[pol][loc], bf_hi(yw));
            atomicAdd(&cnt[pol][loc], 1.0f);
        }
    }
    __syncthreads();
    int node = b * 256 + t;
    if (node < nv) {
        float2 xi = xv_in[node];
        float dv = deg_v[node];
        float iv = (dv > 0.f) ? rsqrtf(dv) : 0.f;
        float m0 = fmaf(iv, sx[0][t], cnt[0][t] * xi.x);
        float m1 = fmaf(iv, sy[0][t], cnt[0][t] * xi.y);
        float m2 = fmaf(iv, sx[1][t], cnt[1][t] * xi.x);
        float m3 = fmaf(iv, sy[1][t], cnt[1][t] * xi.y);
        float o0 = bias[0] + m0 * W[0] + m1 * W[2] + m2 * W[4] + m3 * W[6] + xi.x * W[8] + xi.y * W[10];
        float o1 = bias[1] + m0 * W[1] + m1 * W[3] + m2 * W[5] + m3 * W[7] + xi.x * W[9] + xi.y * W[11];
        xv_out[node] = make_float2(o0, o1);
        if (writeY) yv_out[node] = packy(iv * o0, iv * o1);
    }
}

__global__ __launch_bounds__(256) void c_layer_kernel(
    const unsigned* __restrict__ bkt_pos, const unsigned* __restrict__ base_pos,
    const unsigned* __restrict__ bkt_neg, const unsigned* __restrict__ base_neg,
    const unsigned* __restrict__ yv, float2* __restrict__ xc,
    const float* __restrict__ deg_c, unsigned* __restrict__ yc,
    const float* __restrict__ W, const float* __restrict__ bias, int nc) {
    __shared__ float sx[2][1024], sy[2][1024], cnt[2][1024];
    int b = blockIdx.x, t = threadIdx.x;
    for (int k = 0; k < 4; ++k) {
        int j = t + 256 * k;
        sx[0][j] = 0.f; sx[1][j] = 0.f; sy[0][j] = 0.f; sy[1][j] = 0.f;
        cnt[0][j] = 0.f; cnt[1][j] = 0.f;
    }
    __syncthreads();
    for (int pol = 0; pol < 2; ++pol) {
        const unsigned* bkt = pol ? bkt_neg : bkt_pos;
        const unsigned* bse = pol ? base_neg : base_pos;
        unsigned s = bse[b], epos = bse[b + 1];
        for (unsigned i = s + t; i < epos; i += 256) {
            unsigned u = bkt[i];
            unsigned v = u >> 10;
            int loc = (int)(u & 1023u);
            unsigned yw = yv[v];
            atomicAdd(&sx[pol][loc], bf_lo(yw));
            atomicAdd(&sy[pol][loc], bf_hi(yw));
            atomicAdd(&cnt[pol][loc], 1.0f);
        }
    }
    __syncthreads();
    for (int k = 0; k < 4; ++k) {
        int j = t + 256 * k;
        int node = b * 1024 + j;
        if (node < nc) {
            float2 xi = xc[node];
            float dc = deg_c[node];
            float ic = (dc > 0.f) ? rsqrtf(dc) : 0.f;
            float m0 = fmaf(ic, sx[0][j], cnt[0][j] * xi.x);
            float m1 = fmaf(ic, sy[0][j], cnt[0][j] * xi.y);
            float m2 = fmaf(ic, sx[1][j], cnt[1][j] * xi.x);
            float m3 = fmaf(ic, sy[1][j], cnt[1][j] * xi.y);
            float o0 = bias[0] + m0 * W[0] + m1 * W[2] + m2 * W[4] + m3 * W[6] + xi.x * W[8] + xi.y * W[10];
            float o1 = bias[1] + m0 * W[1] + m1 * W[3] + m2 * W[5] + m3 * W[7] + xi.x * W[9] + xi.y * W[11];
            xc[node] = make_float2(o0, o1);
            yc[node] = packy(ic * o0, ic * o1);
        }
    }
}

// ---------------- fallback B: global-atomic path ----------------

__global__ void init_nodes(const float* __restrict__ x, const float* __restrict__ deg,
                           const float* __restrict__ W0, const float* __restrict__ b0,
                           float2* __restrict__ xf, float* __restrict__ inv, int n) {
    int i = blockIdx.x * blockDim.x + threadIdx.x;
    if (i >= n) return;
    float xi = x[i];
    xf[i] = make_float2(fmaf(xi, W0[0], b0[0]), fmaf(xi, W0[1], b0[1]));
    float d = deg[i];
    inv[i] = (d > 0.0f) ? (1.0f / sqrtf(d)) : 0.0f;
}

__global__ void count_edges(const int* __restrict__ src, const int* __restrict__ trg,
                            float* __restrict__ cnt_src, float* __restrict__ cnt_trg, int e) {
    int i = blockIdx.x * blockDim.x + threadIdx.x;
    if (i >= e) return;
    atomicAdd(&cnt_src[src[i]], 1.0f);
    atomicAdd(&cnt_trg[trg[i]], 1.0f);
}

__global__ void edge_pass(const int* __restrict__ src, const int* __restrict__ trg,
                          const float2* __restrict__ xc, const float2* __restrict__ xv,
                          const float* __restrict__ inv_c, const float* __restrict__ inv_v,
                          float2* __restrict__ Sv, float2* __restrict__ Sc, int e) {
    int i = blockIdx.x * blockDim.x + threadIdx.x;
    if (i >= e) return;
    int c = src[i];
    int v = trg[i];
    float ic = inv_c[c], iv = inv_v[v];
    float2 a = xc[c];
    float2 b = xv[v];
    atomicAdd(&Sv[v].x, a.x * ic);
    atomicAdd(&Sv[v].y, a.y * ic);
    atomicAdd(&Sc[c].x, b.x * iv);
    atomicAdd(&Sc[c].y, b.y * iv);
}

__global__ void node_update(float2* __restrict__ x, const float2* __restrict__ Sp,
                            const float2* __restrict__ Sn, const float* __restrict__ inv,
                            const float* __restrict__ cp, const float* __restrict__ cn,
                            const float* __restrict__ W, const float* __restrict__ b, int n) {
    int i = blockIdx.x * blockDim.x + threadIdx.x;
    if (i >= n) return;
    float2 xi = x[i];
    float ii = inv[i];
    float2 sp = Sp[i], sn = Sn[i];
    float cpi = cp[i], cni = cn[i];
    float m0 = fmaf(ii, sp.x, cpi * xi.x);
    float m1 = fmaf(ii, sp.y, cpi * xi.y);
    float m2 = fmaf(ii, sn.x, cni * xi.x);
    float m3 = fmaf(ii, sn.y, cni * xi.y);
    float o0 = b[0] + m0 * W[0] + m1 * W[2] + m2 * W[4] + m3 * W[6] + xi.x * W[8] + xi.y * W[10];
    float o1 = b[1] + m0 * W[1] + m1 * W[3] + m2 * W[5] + m3 * W[7] + xi.x * W[9] + xi.y * W[11];
    x[i] = make_float2(o0, o1);
}

// ---------------- launch ----------------

extern "C" void kernel_launch(void* const* d_in, const int* in_sizes, int n_in,
                              void* d_out, int out_size, void* d_ws, size_t ws_size,
                              hipStream_t stream) {
    const float* x_clause   = (const float*)d_in[0];
    const float* x_variable = (const float*)d_in[1];
    const float* deg_clause = (const float*)d_in[2];
    const float* deg_var    = (const float*)d_in[3];
    const int*   pos_src    = (const int*)d_in[4];
    const int*   pos_trg    = (const int*)d_in[5];
    const int*   neg_src    = (const int*)d_in[6];
    const int*   neg_trg    = (const int*)d_in[7];
    const float* W0c        = (const float*)d_in[8];
    const float* b0c        = (const float*)d_in[9];
    const float* W0v        = (const float*)d_in[10];
    const float* b0v        = (const float*)d_in[11];
    const float* Wc         = (const float*)d_in[12];
    const float* bc         = (const float*)d_in[13];
    const float* Wv         = (const float*)d_in[14];
    const float* bv         = (const float*)d_in[15];

    const int nc = in_sizes[0];
    const int nv = in_sizes[1];
    const int e  = in_sizes[4];
    const int B = 256;

    const int NBV = cdiv_h(nv, 256);
    const int NBC = cdiv_h(nc, 1024);
    const int maxnb = NBV > NBC ? NBV : NBC;
    const bool pack_ok = (NBV <= 2048) && (NBC <= 2048) && (nc <= (1 << 21)) && (nv <= (1 << 19));

    // -------- full CSR path layout --------
    {
        size_t off = 0;
        auto alloc = [&](size_t bytes) {
            void* p = (char*)d_ws + off;
            off += (bytes + 255) & ~(size_t)255;
            return p;
        };
        unsigned* srcs_vp = (unsigned*)alloc((size_t)e * 4);
        unsigned* srcs_vn = (unsigned*)alloc((size_t)e * 4);
        unsigned* srcs_cp = (unsigned*)alloc((size_t)e * 4);
        unsigned* srcs_cn = (unsigned*)alloc((size_t)e * 4);
        unsigned* rp_vp   = (unsigned*)alloc((size_t)(nv + 1) * 4);
        unsigned* rp_vn   = (unsigned*)alloc((size_t)(nv + 1) * 4);
        unsigned* rp_cp   = (unsigned*)alloc((size_t)(nc + 1) * 4);
        unsigned* rp_cn   = (unsigned*)alloc((size_t)(nc + 1) * 4);
        unsigned* temp    = (unsigned*)alloc((size_t)e * 4);
        unsigned* hist    = (unsigned*)alloc((size_t)maxnb * GAB * 4);
        unsigned* rowscan = (unsigned*)alloc((size_t)maxnb * GAB * 4);
        unsigned* row_tot = (unsigned*)alloc((size_t)maxnb * 4);
        unsigned* baseb   = (unsigned*)alloc((size_t)(maxnb + 1) * 4);
        float2*   xc      = (float2*)alloc((size_t)nc * 8);
        unsigned* yc      = (unsigned*)alloc((size_t)nc * 4);
        float2*   xvB     = (float2*)alloc((size_t)nv * 8);
        unsigned* yvA     = (unsigned*)alloc((size_t)nv * 4);
        unsigned* yvB     = (unsigned*)alloc((size_t)nv * 4);

        if (off <= ws_size && pack_ok) {
            const int chunk = cdiv_h(e, GAB);
            struct { const int* key; const int* pay; int shift; int nb; int bw;
                     unsigned* srcs; unsigned* rp; int n; } V[4] = {
                { pos_trg, pos_src,  8, NBV,  256, srcs_vp, rp_vp, nv },
                { neg_trg, neg_src,  8, NBV,  256, srcs_vn, rp_vn, nv },
                { pos_src, pos_trg, 10, NBC, 1024, srcs_cp, rp_cp, nc },
                { neg_src, neg_trg, 10, NBC, 1024, srcs_cn, rp_cn, nc },
            };
            for (int i = 0; i < 4; ++i) {
                size_t smem = (size_t)V[i].nb * 4;
                hist_kernel<<<GAB, B, smem, stream>>>(V[i].key, e, chunk, V[i].shift, V[i].nb, hist);
                rowscan256<<<V[i].nb, B, 0, stream>>>(hist, rowscan, row_tot);
                basescan_kernel<<<1, 1024, 0, stream>>>(row_tot, baseb, V[i].nb);
                scatter_kernel<<<GAB, B, smem, stream>>>(V[i].key, V[i].pay, e, chunk, V[i].shift,
                                                         (1 << V[i].shift) - 1, V[i].nb,
                                                         rowscan, baseb, temp);
                if (V[i].bw == 256)
                    localsort_kernel<256><<<V[i].nb, B, 0, stream>>>(temp, baseb, V[i].nb, V[i].n,
                                                                     V[i].shift, V[i].srcs, V[i].rp);
                else
                    localsort_kernel<1024><<<V[i].nb, B, 0, stream>>>(temp, baseb, V[i].nb, V[i].n,
                                                                      V[i].shift, V[i].srcs, V[i].rp);
            }

            float2* xvA = (float2*)d_out;  // A->B->A->B->A: final lands in d_out
            init_c_kernel<<<cdiv_h(nc, B), B, 0, stream>>>(x_clause, deg_clause, W0c, b0c, xc, yc, nc);
            init_v_kernel<<<cdiv_h(nv, B), B, 0, stream>>>(x_variable, deg_var, W0v, b0v, xvA, yvA, nv);

            float2* cur = xvA;  float2* nxt = xvB;
            unsigned* ycur = yvA; unsigned* ynxt = yvB;
            for (int l = 0; l < 4; ++l) {
                v_layer_csr<<<cdiv_h(nv, B), B, 0, stream>>>(rp_vp, srcs_vp, rp_vn, srcs_vn,
                                                             yc, cur, deg_var, Wv + l * 12, bv + l * 2,
                                                             nxt, ynxt, nv, (l < 3) ? 1 : 0);
                if (l < 3) {
                    c_layer_csr<<<cdiv_h(nc, B), B, 0, stream>>>(rp_cp, srcs_cp, rp_cn, srcs_cn,
                                                                 ycur, xc, deg_clause, yc,
                                                                 Wc + l * 12, bc + l * 2, nc);
                }
                float2* tx = cur; cur = nxt; nxt = tx;
                unsigned* ty = ycur; ycur = ynxt; ynxt = ty;
            }
            return;
        }
    }

    // -------- fallback A: round-3 bucket-LDS path --------
    {
        size_t off = 0;
        auto alloc = [&](size_t bytes) {
            void* p = (char*)d_ws + off;
            off += (bytes + 255) & ~(size_t)255;
            return p;
        };
        unsigned* cview_p = (unsigned*)alloc((size_t)e * 4);
        unsigned* cview_n = (unsigned*)alloc((size_t)e * 4);
        unsigned* vview_p = (unsigned*)alloc((size_t)e * 4);
        unsigned* vview_n = (unsigned*)alloc((size_t)e * 4);
        unsigned* hist    = (unsigned*)alloc((size_t)maxnb * GAB * 4);
        unsigned* rowscan = (unsigned*)alloc((size_t)maxnb * GAB * 4);
        unsigned* row_tot = (unsigned*)alloc((size_t)maxnb * 4);
        unsigned* base_cp = (unsigned*)alloc((size_t)(NBC + 1) * 4);
        unsigned* base_cn = (unsigned*)alloc((size_t)(NBC + 1) * 4);
        unsigned* base_vp = (unsigned*)alloc((size_t)(NBV + 1) * 4);
        unsigned* base_vn = (unsigned*)alloc((size_t)(NBV + 1) * 4);
        float2*   xc      = (float2*)alloc((size_t)nc * 8);
        unsigned* yc      = (unsigned*)alloc((size_t)nc * 4);
        float2*   xvB     = (float2*)alloc((size_t)nv * 8);
        unsigned* yvA     = (unsigned*)alloc((size_t)nv * 4);
        unsigned* yvB     = (unsigned*)alloc((size_t)nv * 4);

        if (off <= ws_size && pack_ok) {
            const int chunk = cdiv_h(e, GAB);
            struct { const int* key; const int* pay; unsigned* cv; unsigned* bcx; unsigned* vv; unsigned* bvx; } L[2] = {
                { pos_src, pos_trg, cview_p, base_cp, vview_p, base_vp },
                { neg_src, neg_trg, cview_n, base_cn, vview_n, base_vn },
            };
            for (int p = 0; p < 2; ++p) {
                hist_kernel<<<GAB, B, (size_t)NBC * 4, stream>>>(L[p].key, e, chunk, 10, NBC, hist);
                rowscan256<<<NBC, B, 0, stream>>>(hist, rowscan, row_tot);
                basescan_kernel<<<1, 1024, 0, stream>>>(row_tot, L[p].bcx, NBC);
                scatter_kernel<<<GAB, B, (size_t)NBC * 4, stream>>>(L[p].key, L[p].pay, e, chunk,
                                                                    10, 1023, NBC, rowscan, L[p].bcx, L[p].cv);
                hist_kernel<<<GAB, B, (size_t)NBV * 4, stream>>>((const int*)L[p].cv, e, chunk, 18, NBV, hist);
                rowscan256<<<NBV, B, 0, stream>>>(hist, rowscan, row_tot);
                basescan_kernel<<<1, 1024, 0, stream>>>(row_tot, L[p].bvx, NBV);
                vscatter_kernel<<<GAB, B, (size_t)(NBV + NBC + 1) * 4, stream>>>(
                    L[p].cv, e, chunk, NBC, L[p].bcx, rowscan, L[p].bvx, NBV, L[p].vv);
            }

            float2* xvA = (float2*)d_out;
            init_c_kernel<<<cdiv_h(nc, B), B, 0, stream>>>(x_clause, deg_clause, W0c, b0c, xc, yc, nc);
            init_v_kernel<<<cdiv_h(nv, B), B, 0, stream>>>(x_variable, deg_var, W0v, b0v, xvA, yvA, nv);

            float2* cur = xvA;  float2* nxt = xvB;
            unsigned* ycur = yvA; unsigned* ynxt = yvB;
            for (int l = 0; l < 4; ++l) {
                v_layer_kernel<<<NBV, B, 0, stream>>>(vview_p, base_vp, vview_n, base_vn,
                                                      yc, cur, deg_var, Wv + l * 12, bv + l * 2,
                                                      nxt, ynxt, nv, (l < 3) ? 1 : 0);
                if (l < 3) {
                    c_layer_kernel<<<NBC, B, 0, stream>>>(cview_p, base_cp, cview_n, base_cn,
                                                          ycur, xc, deg_clause, yc,
                                                          Wc + l * 12, bc + l * 2, nc);
                }
                float2* tx = cur; cur = nxt; nxt = tx;
                unsigned* ty = ycur; ycur = ynxt; ynxt = ty;
            }
            return;
        }
    }

    // -------- fallback B: global-atomic path --------
    char* p = (char*)d_ws;
    float2* Sv_pos = (float2*)p; p += (size_t)nv * sizeof(float2);
    float2* Sv_neg = (float2*)p; p += (size_t)nv * sizeof(float2);
    float2* Sc_pos = (float2*)p; p += (size_t)nc * sizeof(float2);
    float2* Sc_neg = (float2*)p; p += (size_t)nc * sizeof(float2);
    const size_t s_bytes = (size_t)(2 * nv + 2 * nc) * sizeof(float2);
    float2* xc2 = (float2*)p; p += (size_t)nc * sizeof(float2);
    float* inv_c = (float*)p; p += (size_t)nc * sizeof(float);
    float* inv_v = (float*)p; p += (size_t)nv * sizeof(float);
    float* cntc_pos = (float*)p; p += (size_t)nc * sizeof(float);
    float* cntc_neg = (float*)p; p += (size_t)nc * sizeof(float);
    float* cntv_pos = (float*)p; p += (size_t)nv * sizeof(float);
    float* cntv_neg = (float*)p; p += (size_t)nv * sizeof(float);
    const size_t cnt_bytes = (size_t)(2 * nc + 2 * nv) * sizeof(float);
    float2* xv = (float2*)d_out;

    hipMemsetAsync(Sv_pos, 0, s_bytes, stream);
    hipMemsetAsync(cntc_pos, 0, cnt_bytes, stream);
    init_nodes<<<cdiv_h(nc, B), B, 0, stream>>>(x_clause, deg_clause, W0c, b0c, xc2, inv_c, nc);
    init_nodes<<<cdiv_h(nv, B), B, 0, stream>>>(x_variable, deg_var, W0v, b0v, xv, inv_v, nv);
    count_edges<<<cdiv_h(e, B), B, 0, stream>>>(pos_src, pos_trg, cntc_pos, cntv_pos, e);
    count_edges<<<cdiv_h(e, B), B, 0, stream>>>(neg_src, neg_trg, cntc_neg, cntv_neg, e);
    for (int l = 0; l < 4; ++l) {
        edge_pass<<<cdiv_h(e, B), B, 0, stream>>>(pos_src, pos_trg, xc2, xv, inv_c, inv_v,
                                                  Sv_pos, Sc_pos, e);
        edge_pass<<<cdiv_h(e, B), B, 0, stream>>>(neg_src, neg_trg, xc2, xv, inv_c, inv_v,
                                                  Sv_neg, Sc_neg, e);
        node_update<<<cdiv_h(nv, B), B, 0, stream>>>(xv, Sv_pos, Sv_neg, inv_v,
                                                     cntv_pos, cntv_neg, Wv + l * 12, bv + l * 2, nv);
        node_update<<<cdiv_h(nc, B), B, 0, stream>>>(xc2, Sc_pos, Sc_neg, inv_c,
                                                     cntc_pos, cntc_neg, Wc + l * 12, bc + l * 2, nc);
        if (l < 3) hipMemsetAsync(Sv_pos, 0, s_bytes, stream);
    }
}

// Round 5
// 1459.680 us; speedup vs baseline: 1.3432x; 1.3432x over previous
//
#include <hip/hip_runtime.h>

// G4GCN: 4-layer linear bipartite GNN (clauses <-> variables), feature dim 2.
//
// Round-4 lesson: v-side CSR gather missed L2 (yc = 8MB > 4MB/XCD L2):
// FETCH 779MB/dispatch = 12M x 64B lines from the L3 fabric at 3.5 TB/s.
// Round-5: L2-blocked gather. Clauses split into 4 chunks (yc chunk = 2MB,
// L2-resident). v-view CSR rows are subdivided by chunk at build time
// (localsort key = (v&255)<<2 | chunk, rp stored chunk-major in 4 planes).
// Per layer: 4 chunk passes accumulate into a global float4 acc; then
// c_layer (yv 2MB stays L2-resident, unchunked); then v_finish (in-place
// node update in d_out). No atomics anywhere in the per-layer kernels.

#define GAB 256  // blocks for build hist/scatter passes

static inline int cdiv_h(long long a, long long b) { return (int)((a + b - 1) / b); }

__device__ inline float bf_lo(unsigned u) { return __uint_as_float(u << 16); }
__device__ inline float bf_hi(unsigned u) { return __uint_as_float(u & 0xffff0000u); }
__device__ inline unsigned packy(float a, float b) {
    unsigned ua = __float_as_uint(a), ub = __float_as_uint(b);
    ua = (ua + 0x7fffu + ((ua >> 16) & 1u)) >> 16;
    ub = (ub + 0x7fffu + ((ub >> 16) & 1u)) & 0xffff0000u;
    return ua | ub;
}

// ---------------- build: counting partition ----------------

__global__ void hist_kernel(const int* __restrict__ key, int e, int chunk, int shift,
                            int nb, unsigned* __restrict__ hist /*[nb][GAB]*/) {
    extern __shared__ unsigned h[];
    int blk = blockIdx.x, tid = threadIdx.x;
    for (int i = tid; i < nb; i += blockDim.x) h[i] = 0u;
    __syncthreads();
    int s = blk * chunk, epos = min(e, s + chunk);
    for (int i = s + tid; i < epos; i += blockDim.x)
        atomicAdd(&h[key[i] >> shift], 1u);
    __syncthreads();
    for (int i = tid; i < nb; i += blockDim.x) hist[(size_t)i * GAB + blk] = h[i];
}

__global__ void rowscan256(const unsigned* __restrict__ hist, unsigned* __restrict__ rowscan,
                           unsigned* __restrict__ row_total) {
    __shared__ unsigned ts[256];
    int b = blockIdx.x, t = threadIdx.x;
    unsigned v0 = hist[(size_t)b * GAB + t];
    ts[t] = v0;
    __syncthreads();
    for (int off = 1; off < 256; off <<= 1) {
        unsigned v = (t >= off) ? ts[t - off] : 0u;
        __syncthreads();
        ts[t] += v;
        __syncthreads();
    }
    rowscan[(size_t)b * GAB + t] = ts[t] - v0;
    if (t == 255) row_total[b] = ts[255];
}

__global__ void basescan_kernel(const unsigned* __restrict__ row_total,
                                unsigned* __restrict__ base, int nb) {
    __shared__ unsigned a[2048];
    __shared__ unsigned ts[1024];
    int t = threadIdx.x;
    a[t] = (t < nb) ? row_total[t] : 0u;
    a[t + 1024] = (t + 1024 < nb) ? row_total[t + 1024] : 0u;
    __syncthreads();
    unsigned a0 = a[2 * t], a1 = a[2 * t + 1];
    unsigned sum = a0 + a1;
    ts[t] = sum;
    __syncthreads();
    for (int off = 1; off < 1024; off <<= 1) {
        unsigned v = (t >= off) ? ts[t - off] : 0u;
        __syncthreads();
        ts[t] += v;
        __syncthreads();
    }
    unsigned b0 = ts[t] - sum;
    if (2 * t <= nb) base[2 * t] = b0;
    if (2 * t + 1 <= nb) base[2 * t + 1] = b0 + a0;
}

// c-view scatter: bucket by clause (key>>10); entry = (v << 10) | (c & 1023)
__global__ void scatter_kernel(const int* __restrict__ key, const int* __restrict__ payload,
                               int e, int chunk, int shift, int mask, int nb,
                               const unsigned* __restrict__ rowscan,
                               const unsigned* __restrict__ base,
                               unsigned* __restrict__ out) {
    extern __shared__ unsigned cur[];
    int blk = blockIdx.x, tid = threadIdx.x;
    for (int i = tid; i < nb; i += blockDim.x)
        cur[i] = base[i] + rowscan[(size_t)i * GAB + blk];
    __syncthreads();
    int s = blk * chunk, epos = min(e, s + chunk);
    for (int i = s + tid; i < epos; i += blockDim.x) {
        int k = key[i];
        int b = k >> shift;
        unsigned p = atomicAdd(&cur[b], 1u);
        out[p] = ((unsigned)payload[i] << shift) | (unsigned)(k & mask);
    }
}

// v-view scatter: bucket by trg>>8; entry = (c << 10) | ((v & 255) << 2) | (c >> cs)
__global__ void scatter_v_kernel(const int* __restrict__ trg, const int* __restrict__ src,
                                 int e, int chunk, int cs, int nb,
                                 const unsigned* __restrict__ rowscan,
                                 const unsigned* __restrict__ base,
                                 unsigned* __restrict__ out) {
    extern __shared__ unsigned cur[];
    int blk = blockIdx.x, tid = threadIdx.x;
    for (int i = tid; i < nb; i += blockDim.x)
        cur[i] = base[i] + rowscan[(size_t)i * GAB + blk];
    __syncthreads();
    int s = blk * chunk, epos = min(e, s + chunk);
    for (int i = s + tid; i < epos; i += blockDim.x) {
        unsigned v = (unsigned)trg[i];
        unsigned c = (unsigned)src[i];
        unsigned p = atomicAdd(&cur[v >> 8], 1u);
        out[p] = (c << 10) | ((v & 255u) << 2) | (c >> cs);
    }
}

// c-view localsort: per 1024-clause bucket, counting sort by (c & 1023).
// Produces srcs (= variable ids) ordered by clause, and linear rp[nc+1].
__global__ __launch_bounds__(256) void localsort_c_kernel(
    const unsigned* __restrict__ ent, const unsigned* __restrict__ base,
    int nb, int n, unsigned* __restrict__ srcs, unsigned* __restrict__ rp) {
    __shared__ unsigned h[1024];
    __shared__ unsigned ts[256];
    int b = blockIdx.x, t = threadIdx.x;
    unsigned s = base[b], eend = base[b + 1];
    for (int k = 0; k < 4; ++k) h[t * 4 + k] = 0u;
    __syncthreads();
    for (unsigned i = s + t; i < eend; i += 256)
        atomicAdd(&h[ent[i] & 1023u], 1u);
    __syncthreads();
    unsigned v0[4];
    unsigned sum = 0;
    for (int k = 0; k < 4; ++k) { v0[k] = h[t * 4 + k]; sum += v0[k]; }
    ts[t] = sum;
    __syncthreads();
    for (int off = 1; off < 256; off <<= 1) {
        unsigned x = (t >= off) ? ts[t - off] : 0u;
        __syncthreads();
        ts[t] += x;
        __syncthreads();
    }
    unsigned ex = ts[t] - sum;
    unsigned hx[4];
    for (int k = 0; k < 4; ++k) { hx[k] = ex; ex += v0[k]; }
    for (int k = 0; k < 4; ++k) {
        int idx = b * 1024 + t * 4 + k;
        if (idx < n) rp[idx] = s + hx[k];
        h[t * 4 + k] = hx[k];
    }
    if (b == nb - 1 && t == 0) rp[n] = eend;
    __syncthreads();
    for (unsigned i = s + t; i < eend; i += 256) {
        unsigned u = ent[i];
        unsigned p = s + atomicAdd(&h[u & 1023u], 1u);
        srcs[p] = u >> 10;
    }
}

// v-view localsort: per 256-variable bucket, counting sort by (v&255)<<2|chunk.
// Produces srcs (= clause ids) and rp in 4 chunk-major planes of (nv+1).
__global__ __launch_bounds__(256) void localsort_v_kernel(
    const unsigned* __restrict__ ent, const unsigned* __restrict__ base,
    int nb, int nv, unsigned* __restrict__ srcs, unsigned* __restrict__ rp) {
    __shared__ unsigned h[1024];
    __shared__ unsigned ts[256];
    int b = blockIdx.x, t = threadIdx.x;
    unsigned s = base[b], eend = base[b + 1];
    for (int k = 0; k < 4; ++k) h[t * 4 + k] = 0u;
    __syncthreads();
    for (unsigned i = s + t; i < eend; i += 256)
        atomicAdd(&h[ent[i] & 1023u], 1u);
    __syncthreads();
    unsigned v0[4];
    unsigned sum = 0;
    for (int k = 0; k < 4; ++k) { v0[k] = h[t * 4 + k]; sum += v0[k]; }
    ts[t] = sum;
    __syncthreads();
    for (int off = 1; off < 256; off <<= 1) {
        unsigned x = (t >= off) ? ts[t - off] : 0u;
        __syncthreads();
        ts[t] += x;
        __syncthreads();
    }
    unsigned ex = ts[t] - sum;
    unsigned hx[4];
    for (int k = 0; k < 4; ++k) { hx[k] = ex; ex += v0[k]; }
    int node = b * 256 + t;  // key layout: idx = t*4 + k -> (node_local=t, chunk=k)
    if (node < nv) {
        for (int k = 0; k < 4; ++k) rp[(size_t)k * (nv + 1) + node] = s + hx[k];
    }
    if (b == nb - 1 && t == 0) rp[nv] = eend;  // plane-0 sentinel
    for (int k = 0; k < 4; ++k) h[t * 4 + k] = hx[k];
    __syncthreads();
    for (unsigned i = s + t; i < eend; i += 256) {
        unsigned u = ent[i];
        unsigned p = s + atomicAdd(&h[u & 1023u], 1u);
        srcs[p] = u >> 10;
    }
}

// ---------------- node init ----------------

__global__ void init_c_kernel(const float* __restrict__ x, const float* __restrict__ deg,
                              const float* __restrict__ W0, const float* __restrict__ b0,
                              float2* __restrict__ xc, unsigned* __restrict__ yc, int n) {
    int i = blockIdx.x * blockDim.x + threadIdx.x;
    if (i >= n) return;
    float xi = x[i];
    float2 o = make_float2(fmaf(xi, W0[0], b0[0]), fmaf(xi, W0[1], b0[1]));
    xc[i] = o;
    float d = deg[i];
    float inv = (d > 0.f) ? rsqrtf(d) : 0.f;
    yc[i] = packy(inv * o.x, inv * o.y);
}

__global__ void init_v_kernel(const float* __restrict__ x, const float* __restrict__ deg,
                              const float* __restrict__ W0, const float* __restrict__ b0,
                              float2* __restrict__ xv, unsigned* __restrict__ yv, int n) {
    int i = blockIdx.x * blockDim.x + threadIdx.x;
    if (i >= n) return;
    float xi = x[i];
    float2 o = make_float2(fmaf(xi, W0[0], b0[0]), fmaf(xi, W0[1], b0[1]));
    xv[i] = o;
    float d = deg[i];
    float inv = (d > 0.f) ? rsqrtf(d) : 0.f;
    yv[i] = packy(inv * o.x, inv * o.y);
}

// ---------------- per-layer kernels (no LDS, no atomics) ----------------

// One clause-chunk pass: gathers stay inside a 2MB window of yc (L2-resident).
__global__ __launch_bounds__(256) void v_chunk_pass(
    const unsigned* __restrict__ sp_p, const unsigned* __restrict__ ep_p,
    const unsigned* __restrict__ src_p,
    const unsigned* __restrict__ sp_n, const unsigned* __restrict__ ep_n,
    const unsigned* __restrict__ src_n,
    const unsigned* __restrict__ yc, float4* __restrict__ acc, int nv, int initf) {
    int i = blockIdx.x * blockDim.x + threadIdx.x;
    if (i >= nv) return;
    float4 a = initf ? make_float4(0.f, 0.f, 0.f, 0.f) : acc[i];
    unsigned s0 = sp_p[i], e0 = ep_p[i];
    for (unsigned j = s0; j < e0; ++j) {
        unsigned yw = yc[src_p[j]];
        a.x += bf_lo(yw); a.y += bf_hi(yw);
    }
    unsigned s1 = sp_n[i], e1 = ep_n[i];
    for (unsigned j = s1; j < e1; ++j) {
        unsigned yw = yc[src_n[j]];
        a.z += bf_lo(yw); a.w += bf_hi(yw);
    }
    acc[i] = a;
}

__global__ __launch_bounds__(256) void v_finish_kernel(
    const float4* __restrict__ acc, const unsigned* __restrict__ rp0_p,
    const unsigned* __restrict__ rp0_n, float2* __restrict__ xv,
    const float* __restrict__ deg_v, const float* __restrict__ W,
    const float* __restrict__ bias, unsigned* __restrict__ yv_out, int nv, int writeY) {
    int i = blockIdx.x * blockDim.x + threadIdx.x;
    if (i >= nv) return;
    float4 a = acc[i];
    float cp = (float)(rp0_p[i + 1] - rp0_p[i]);
    float cn = (float)(rp0_n[i + 1] - rp0_n[i]);
    float2 xi = xv[i];
    float dv = deg_v[i];
    float iv = (dv > 0.f) ? rsqrtf(dv) : 0.f;
    float m0 = fmaf(iv, a.x, cp * xi.x);
    float m1 = fmaf(iv, a.y, cp * xi.y);
    float m2 = fmaf(iv, a.z, cn * xi.x);
    float m3 = fmaf(iv, a.w, cn * xi.y);
    float o0 = bias[0] + m0 * W[0] + m1 * W[2] + m2 * W[4] + m3 * W[6] + xi.x * W[8] + xi.y * W[10];
    float o1 = bias[1] + m0 * W[1] + m1 * W[3] + m2 * W[5] + m3 * W[7] + xi.x * W[9] + xi.y * W[11];
    xv[i] = make_float2(o0, o1);
    if (writeY) yv_out[i] = packy(iv * o0, iv * o1);
}

__global__ __launch_bounds__(256) void c_layer_csr(
    const unsigned* __restrict__ rp_p, const unsigned* __restrict__ src_p,
    const unsigned* __restrict__ rp_n, const unsigned* __restrict__ src_n,
    const unsigned* __restrict__ yv, float2* __restrict__ xc,
    const float* __restrict__ deg_c, unsigned* __restrict__ yc,
    const float* __restrict__ W, const float* __restrict__ bias, int nc) {
    int i = blockIdx.x * blockDim.x + threadIdx.x;
    if (i >= nc) return;
    unsigned s0 = rp_p[i], e0 = rp_p[i + 1];
    unsigned s1 = rp_n[i], e1 = rp_n[i + 1];
    float ax = 0.f, ay = 0.f, bx = 0.f, by = 0.f;
    for (unsigned j = s0; j < e0; ++j) {
        unsigned yw = yv[src_p[j]];
        ax += bf_lo(yw); ay += bf_hi(yw);
    }
    for (unsigned j = s1; j < e1; ++j) {
        unsigned yw = yv[src_n[j]];
        bx += bf_lo(yw); by += bf_hi(yw);
    }
    float cp = (float)(e0 - s0), cn = (float)(e1 - s1);
    float2 xi = xc[i];
    float dc = deg_c[i];
    float ic = (dc > 0.f) ? rsqrtf(dc) : 0.f;
    float m0 = fmaf(ic, ax, cp * xi.x);
    float m1 = fmaf(ic, ay, cp * xi.y);
    float m2 = fmaf(ic, bx, cn * xi.x);
    float m3 = fmaf(ic, by, cn * xi.y);
    float o0 = bias[0] + m0 * W[0] + m1 * W[2] + m2 * W[4] + m3 * W[6] + xi.x * W[8] + xi.y * W[10];
    float o1 = bias[1] + m0 * W[1] + m1 * W[3] + m2 * W[5] + m3 * W[7] + xi.x * W[9] + xi.y * W[11];
    xc[i] = make_float2(o0, o1);
    yc[i] = packy(ic * o0, ic * o1);
}

// ---------------- fallback: global-atomic path ----------------

__global__ void init_nodes(const float* __restrict__ x, const float* __restrict__ deg,
                           const float* __restrict__ W0, const float* __restrict__ b0,
                           float2* __restrict__ xf, float* __restrict__ inv, int n) {
    int i = blockIdx.x * blockDim.x + threadIdx.x;
    if (i >= n) return;
    float xi = x[i];
    xf[i] = make_float2(fmaf(xi, W0[0], b0[0]), fmaf(xi, W0[1], b0[1]));
    float d = deg[i];
    inv[i] = (d > 0.0f) ? (1.0f / sqrtf(d)) : 0.0f;
}

__global__ void count_edges(const int* __restrict__ src, const int* __restrict__ trg,
                            float* __restrict__ cnt_src, float* __restrict__ cnt_trg, int e) {
    int i = blockIdx.x * blockDim.x + threadIdx.x;
    if (i >= e) return;
    atomicAdd(&cnt_src[src[i]], 1.0f);
    atomicAdd(&cnt_trg[trg[i]], 1.0f);
}

__global__ void edge_pass(const int* __restrict__ src, const int* __restrict__ trg,
                          const float2* __restrict__ xc, const float2* __restrict__ xv,
                          const float* __restrict__ inv_c, const float* __restrict__ inv_v,
                          float2* __restrict__ Sv, float2* __restrict__ Sc, int e) {
    int i = blockIdx.x * blockDim.x + threadIdx.x;
    if (i >= e) return;
    int c = src[i];
    int v = trg[i];
    float ic = inv_c[c], iv = inv_v[v];
    float2 a = xc[c];
    float2 b = xv[v];
    atomicAdd(&Sv[v].x, a.x * ic);
    atomicAdd(&Sv[v].y, a.y * ic);
    atomicAdd(&Sc[c].x, b.x * iv);
    atomicAdd(&Sc[c].y, b.y * iv);
}

__global__ void node_update(float2* __restrict__ x, const float2* __restrict__ Sp,
                            const float2* __restrict__ Sn, const float* __restrict__ inv,
                            const float* __restrict__ cp, const float* __restrict__ cn,
                            const float* __restrict__ W, const float* __restrict__ b, int n) {
    int i = blockIdx.x * blockDim.x + threadIdx.x;
    if (i >= n) return;
    float2 xi = x[i];
    float ii = inv[i];
    float2 sp = Sp[i], sn = Sn[i];
    float cpi = cp[i], cni = cn[i];
    float m0 = fmaf(ii, sp.x, cpi * xi.x);
    float m1 = fmaf(ii, sp.y, cpi * xi.y);
    float m2 = fmaf(ii, sn.x, cni * xi.x);
    float m3 = fmaf(ii, sn.y, cni * xi.y);
    float o0 = b[0] + m0 * W[0] + m1 * W[2] + m2 * W[4] + m3 * W[6] + xi.x * W[8] + xi.y * W[10];
    float o1 = b[1] + m0 * W[1] + m1 * W[3] + m2 * W[5] + m3 * W[7] + xi.x * W[9] + xi.y * W[11];
    x[i] = make_float2(o0, o1);
}

// ---------------- launch ----------------

extern "C" void kernel_launch(void* const* d_in, const int* in_sizes, int n_in,
                              void* d_out, int out_size, void* d_ws, size_t ws_size,
                              hipStream_t stream) {
    const float* x_clause   = (const float*)d_in[0];
    const float* x_variable = (const float*)d_in[1];
    const float* deg_clause = (const float*)d_in[2];
    const float* deg_var    = (const float*)d_in[3];
    const int*   pos_src    = (const int*)d_in[4];
    const int*   pos_trg    = (const int*)d_in[5];
    const int*   neg_src    = (const int*)d_in[6];
    const int*   neg_trg    = (const int*)d_in[7];
    const float* W0c        = (const float*)d_in[8];
    const float* b0c        = (const float*)d_in[9];
    const float* W0v        = (const float*)d_in[10];
    const float* b0v        = (const float*)d_in[11];
    const float* Wc         = (const float*)d_in[12];
    const float* bc         = (const float*)d_in[13];
    const float* Wv         = (const float*)d_in[14];
    const float* bv         = (const float*)d_in[15];

    const int nc = in_sizes[0];
    const int nv = in_sizes[1];
    const int e  = in_sizes[4];
    const int B = 256;

    const int NBV = cdiv_h(nv, 256);
    const int NBC = cdiv_h(nc, 1024);
    const int maxnb = NBV > NBC ? NBV : NBC;
    const bool pack_ok = (NBV <= 2040) && (NBC <= 2040) && (nc <= (1 << 21)) && (nv <= (1 << 21));

    int cs = 0;  // clause-chunk shift: 4 chunks cover nc
    while ((4LL << cs) < nc) cs++;

    // -------- tier-1 layout: persistent arrays + build/layer overlay --------
    {
        size_t off = 0;
        auto alloc = [&](size_t bytes) {
            void* p = (char*)d_ws + off;
            off += (bytes + 255) & ~(size_t)255;
            return p;
        };
        unsigned* srcs_vp = (unsigned*)alloc((size_t)e * 4);
        unsigned* srcs_vn = (unsigned*)alloc((size_t)e * 4);
        unsigned* srcs_cp = (unsigned*)alloc((size_t)e * 4);
        unsigned* srcs_cn = (unsigned*)alloc((size_t)e * 4);
        unsigned* rp_vp   = (unsigned*)alloc((size_t)4 * (nv + 1) * 4);  // 4 chunk-major planes
        unsigned* rp_vn   = (unsigned*)alloc((size_t)4 * (nv + 1) * 4);
        unsigned* rp_cp   = (unsigned*)alloc((size_t)(nc + 1) * 4);
        unsigned* rp_cn   = (unsigned*)alloc((size_t)(nc + 1) * 4);
        const size_t overlay = off;
        // build-time view
        unsigned* temp    = (unsigned*)alloc((size_t)e * 4);
        unsigned* hist    = (unsigned*)alloc((size_t)maxnb * GAB * 4);
        unsigned* rowscan = (unsigned*)alloc((size_t)maxnb * GAB * 4);
        unsigned* row_tot = (unsigned*)alloc((size_t)maxnb * 4);
        unsigned* baseb   = (unsigned*)alloc((size_t)(maxnb + 1) * 4);
        const size_t build_end = off;
        // layer-time view (overlaps build scratch; inits run AFTER build)
        off = overlay;
        float4*   accv    = (float4*)alloc((size_t)nv * 16);
        float2*   xc      = (float2*)alloc((size_t)nc * 8);
        unsigned* yc      = (unsigned*)alloc((size_t)nc * 4);
        unsigned* yv      = (unsigned*)alloc((size_t)nv * 4);
        const size_t layer_end = off;
        const size_t required = build_end > layer_end ? build_end : layer_end;

        if (required <= ws_size && pack_ok) {
            const int chunk = cdiv_h(e, GAB);
            // v-views (bucket by v>>8, localsort by (v&255)<<2|clause_chunk)
            const int* vkeys[2] = { pos_trg, neg_trg };
            const int* vpays[2] = { pos_src, neg_src };
            unsigned* vsrcs[2] = { srcs_vp, srcs_vn };
            unsigned* vrps[2]  = { rp_vp, rp_vn };
            for (int p = 0; p < 2; ++p) {
                hist_kernel<<<GAB, B, (size_t)NBV * 4, stream>>>(vkeys[p], e, chunk, 8, NBV, hist);
                rowscan256<<<NBV, B, 0, stream>>>(hist, rowscan, row_tot);
                basescan_kernel<<<1, 1024, 0, stream>>>(row_tot, baseb, NBV);
                scatter_v_kernel<<<GAB, B, (size_t)NBV * 4, stream>>>(vkeys[p], vpays[p], e, chunk,
                                                                      cs, NBV, rowscan, baseb, temp);
                localsort_v_kernel<<<NBV, B, 0, stream>>>(temp, baseb, NBV, nv, vsrcs[p], vrps[p]);
            }
            // c-views (bucket by c>>10, localsort by c&1023)
            const int* ckeys[2] = { pos_src, neg_src };
            const int* cpays[2] = { pos_trg, neg_trg };
            unsigned* csrcs[2] = { srcs_cp, srcs_cn };
            unsigned* crps[2]  = { rp_cp, rp_cn };
            for (int p = 0; p < 2; ++p) {
                hist_kernel<<<GAB, B, (size_t)NBC * 4, stream>>>(ckeys[p], e, chunk, 10, NBC, hist);
                rowscan256<<<NBC, B, 0, stream>>>(hist, rowscan, row_tot);
                basescan_kernel<<<1, 1024, 0, stream>>>(row_tot, baseb, NBC);
                scatter_kernel<<<GAB, B, (size_t)NBC * 4, stream>>>(ckeys[p], cpays[p], e, chunk,
                                                                    10, 1023, NBC, rowscan, baseb, temp);
                localsort_c_kernel<<<NBC, B, 0, stream>>>(temp, baseb, NBC, nc, csrcs[p], crps[p]);
            }

            float2* xv = (float2*)d_out;  // updated in place each layer
            init_c_kernel<<<cdiv_h(nc, B), B, 0, stream>>>(x_clause, deg_clause, W0c, b0c, xc, yc, nc);
            init_v_kernel<<<cdiv_h(nv, B), B, 0, stream>>>(x_variable, deg_var, W0v, b0v, xv, yv, nv);

            const size_t P = (size_t)nv + 1;
            for (int l = 0; l < 4; ++l) {
                for (int k = 0; k < 4; ++k) {
                    const unsigned* ep_p = (k < 3) ? rp_vp + (k + 1) * P : rp_vp + 1;
                    const unsigned* ep_n = (k < 3) ? rp_vn + (k + 1) * P : rp_vn + 1;
                    v_chunk_pass<<<cdiv_h(nv, B), B, 0, stream>>>(
                        rp_vp + k * P, ep_p, srcs_vp,
                        rp_vn + k * P, ep_n, srcs_vn,
                        yc, accv, nv, (k == 0) ? 1 : 0);
                }
                if (l < 3) {
                    // reads yv (= y of xv_l, untouched so far this layer), rewrites xc/yc
                    c_layer_csr<<<cdiv_h(nc, B), B, 0, stream>>>(rp_cp, srcs_cp, rp_cn, srcs_cn,
                                                                 yv, xc, deg_clause, yc,
                                                                 Wc + l * 12, bc + l * 2, nc);
                }
                // in-place xv update; writes yv for the NEXT layer's c_layer (only needed l<2)
                v_finish_kernel<<<cdiv_h(nv, B), B, 0, stream>>>(accv, rp_vp, rp_vn, xv, deg_var,
                                                                 Wv + l * 12, bv + l * 2, yv, nv,
                                                                 (l < 2) ? 1 : 0);
            }
            return;
        }
    }

    // -------- fallback: global-atomic path --------
    char* p = (char*)d_ws;
    float2* Sv_pos = (float2*)p; p += (size_t)nv * sizeof(float2);
    float2* Sv_neg = (float2*)p; p += (size_t)nv * sizeof(float2);
    float2* Sc_pos = (float2*)p; p += (size_t)nc * sizeof(float2);
    float2* Sc_neg = (float2*)p; p += (size_t)nc * sizeof(float2);
    const size_t s_bytes = (size_t)(2 * nv + 2 * nc) * sizeof(float2);
    float2* xc2 = (float2*)p; p += (size_t)nc * sizeof(float2);
    float* inv_c = (float*)p; p += (size_t)nc * sizeof(float);
    float* inv_v = (float*)p; p += (size_t)nv * sizeof(float);
    float* cntc_pos = (float*)p; p += (size_t)nc * sizeof(float);
    float* cntc_neg = (float*)p; p += (size_t)nc * sizeof(float);
    float* cntv_pos = (float*)p; p += (size_t)nv * sizeof(float);
    float* cntv_neg = (float*)p; p += (size_t)nv * sizeof(float);
    const size_t cnt_bytes = (size_t)(2 * nc + 2 * nv) * sizeof(float);
    float2* xv = (float2*)d_out;

    hipMemsetAsync(Sv_pos, 0, s_bytes, stream);
    hipMemsetAsync(cntc_pos, 0, cnt_bytes, stream);
    init_nodes<<<cdiv_h(nc, B), B, 0, stream>>>(x_clause, deg_clause, W0c, b0c, xc2, inv_c, nc);
    init_nodes<<<cdiv_h(nv, B), B, 0, stream>>>(x_variable, deg_var, W0v, b0v, xv, inv_v, nv);
    count_edges<<<cdiv_h(e, B), B, 0, stream>>>(pos_src, pos_trg, cntc_pos, cntv_pos, e);
    count_edges<<<cdiv_h(e, B), B, 0, stream>>>(neg_src, neg_trg, cntc_neg, cntv_neg, e);
    for (int l = 0; l < 4; ++l) {
        edge_pass<<<cdiv_h(e, B), B, 0, stream>>>(pos_src, pos_trg, xc2, xv, inv_c, inv_v,
                                                  Sv_pos, Sc_pos, e);
        edge_pass<<<cdiv_h(e, B), B, 0, stream>>>(neg_src, neg_trg, xc2, xv, inv_c, inv_v,
                                                  Sv_neg, Sc_neg, e);
        node_update<<<cdiv_h(nv, B), B, 0, stream>>>(xv, Sv_pos, Sv_neg, inv_v,
                                                     cntv_pos, cntv_neg, Wv + l * 12, bv + l * 2, nv);
        node_update<<<cdiv_h(nc, B), B, 0, stream>>>(xc2, Sc_pos, Sc_neg, inv_c,
                                                     cntc_pos, cntc_neg, Wc + l * 12, bc + l * 2, nc);
        if (l < 3) hipMemsetAsync(Sv_pos, 0, s_bytes, stream);
    }
}

// Round 6
// 1374.309 us; speedup vs baseline: 1.4266x; 1.0621x over previous
//
#include <hip/hip_runtime.h>

// G4GCN: 4-layer linear bipartite GNN (clauses <-> variables), feature dim 2.
//
// Round-5 lesson: build scatters ran at 9.5% occupancy (256 x 256-thread
// blocks) -> 125us each, latency-bound random 4B writes. Round-6:
//  - hist/scatter at 1024 threads/block (same 256-block deterministic
//    hist+scan structure) -> ~50% occupancy.
//  - v-view rp in node-major layout rp[node*4+chunk]: chunk pass reads
//    (start,end) from adjacent words; rp[i*4+4] = next node's row start,
//    uniform for all 4 chunks. Localsort writes rp as one 16B store.
// Layer structure unchanged from round 5 (L2-blocked v gathers, CSR, no
// atomics in layer kernels).

#define GAB 256   // blocks for build hist/scatter passes
#define BB  1024  // threads for build hist/scatter passes

static inline int cdiv_h(long long a, long long b) { return (int)((a + b - 1) / b); }

__device__ inline float bf_lo(unsigned u) { return __uint_as_float(u << 16); }
__device__ inline float bf_hi(unsigned u) { return __uint_as_float(u & 0xffff0000u); }
__device__ inline unsigned packy(float a, float b) {
    unsigned ua = __float_as_uint(a), ub = __float_as_uint(b);
    ua = (ua + 0x7fffu + ((ua >> 16) & 1u)) >> 16;
    ub = (ub + 0x7fffu + ((ub >> 16) & 1u)) & 0xffff0000u;
    return ua | ub;
}

// ---------------- build: counting partition ----------------

__global__ __launch_bounds__(BB) void hist_kernel(
    const int* __restrict__ key, int e, int chunk, int shift,
    int nb, unsigned* __restrict__ hist /*[nb][GAB]*/) {
    extern __shared__ unsigned h[];
    int blk = blockIdx.x, tid = threadIdx.x;
    for (int i = tid; i < nb; i += blockDim.x) h[i] = 0u;
    __syncthreads();
    int s = blk * chunk, epos = min(e, s + chunk);
    for (int i = s + tid; i < epos; i += blockDim.x)
        atomicAdd(&h[key[i] >> shift], 1u);
    __syncthreads();
    for (int i = tid; i < nb; i += blockDim.x) hist[(size_t)i * GAB + blk] = h[i];
}

__global__ void rowscan256(const unsigned* __restrict__ hist, unsigned* __restrict__ rowscan,
                           unsigned* __restrict__ row_total) {
    __shared__ unsigned ts[256];
    int b = blockIdx.x, t = threadIdx.x;
    unsigned v0 = hist[(size_t)b * GAB + t];
    ts[t] = v0;
    __syncthreads();
    for (int off = 1; off < 256; off <<= 1) {
        unsigned v = (t >= off) ? ts[t - off] : 0u;
        __syncthreads();
        ts[t] += v;
        __syncthreads();
    }
    rowscan[(size_t)b * GAB + t] = ts[t] - v0;
    if (t == 255) row_total[b] = ts[255];
}

__global__ void basescan_kernel(const unsigned* __restrict__ row_total,
                                unsigned* __restrict__ base, int nb) {
    __shared__ unsigned a[2048];
    __shared__ unsigned ts[1024];
    int t = threadIdx.x;
    a[t] = (t < nb) ? row_total[t] : 0u;
    a[t + 1024] = (t + 1024 < nb) ? row_total[t + 1024] : 0u;
    __syncthreads();
    unsigned a0 = a[2 * t], a1 = a[2 * t + 1];
    unsigned sum = a0 + a1;
    ts[t] = sum;
    __syncthreads();
    for (int off = 1; off < 1024; off <<= 1) {
        unsigned v = (t >= off) ? ts[t - off] : 0u;
        __syncthreads();
        ts[t] += v;
        __syncthreads();
    }
    unsigned b0 = ts[t] - sum;
    if (2 * t <= nb) base[2 * t] = b0;
    if (2 * t + 1 <= nb) base[2 * t + 1] = b0 + a0;
}

// c-view scatter: bucket by clause (key>>10); entry = (v << 10) | (c & 1023)
__global__ __launch_bounds__(BB) void scatter_kernel(
    const int* __restrict__ key, const int* __restrict__ payload,
    int e, int chunk, int shift, int mask, int nb,
    const unsigned* __restrict__ rowscan, const unsigned* __restrict__ base,
    unsigned* __restrict__ out) {
    extern __shared__ unsigned cur[];
    int blk = blockIdx.x, tid = threadIdx.x;
    for (int i = tid; i < nb; i += blockDim.x)
        cur[i] = base[i] + rowscan[(size_t)i * GAB + blk];
    __syncthreads();
    int s = blk * chunk, epos = min(e, s + chunk);
    for (int i = s + tid; i < epos; i += blockDim.x) {
        int k = key[i];
        int b = k >> shift;
        unsigned p = atomicAdd(&cur[b], 1u);
        out[p] = ((unsigned)payload[i] << shift) | (unsigned)(k & mask);
    }
}

// v-view scatter: bucket by trg>>8; entry = (c << 10) | ((v & 255) << 2) | chunk(c)
__global__ __launch_bounds__(BB) void scatter_v_kernel(
    const int* __restrict__ trg, const int* __restrict__ src,
    int e, int chunk, int cs, int nb,
    const unsigned* __restrict__ rowscan, const unsigned* __restrict__ base,
    unsigned* __restrict__ out) {
    extern __shared__ unsigned cur[];
    int blk = blockIdx.x, tid = threadIdx.x;
    for (int i = tid; i < nb; i += blockDim.x)
        cur[i] = base[i] + rowscan[(size_t)i * GAB + blk];
    __syncthreads();
    int s = blk * chunk, epos = min(e, s + chunk);
    for (int i = s + tid; i < epos; i += blockDim.x) {
        unsigned v = (unsigned)trg[i];
        unsigned c = (unsigned)src[i];
        unsigned p = atomicAdd(&cur[v >> 8], 1u);
        out[p] = (c << 10) | ((v & 255u) << 2) | (c >> cs);
    }
}

// c-view localsort: per 1024-clause bucket, counting sort by (c & 1023).
__global__ __launch_bounds__(256) void localsort_c_kernel(
    const unsigned* __restrict__ ent, const unsigned* __restrict__ base,
    int nb, int n, unsigned* __restrict__ srcs, unsigned* __restrict__ rp) {
    __shared__ unsigned h[1024];
    __shared__ unsigned ts[256];
    int b = blockIdx.x, t = threadIdx.x;
    unsigned s = base[b], eend = base[b + 1];
    for (int k = 0; k < 4; ++k) h[t * 4 + k] = 0u;
    __syncthreads();
    for (unsigned i = s + t; i < eend; i += 256)
        atomicAdd(&h[ent[i] & 1023u], 1u);
    __syncthreads();
    unsigned v0[4];
    unsigned sum = 0;
    for (int k = 0; k < 4; ++k) { v0[k] = h[t * 4 + k]; sum += v0[k]; }
    ts[t] = sum;
    __syncthreads();
    for (int off = 1; off < 256; off <<= 1) {
        unsigned x = (t >= off) ? ts[t - off] : 0u;
        __syncthreads();
        ts[t] += x;
        __syncthreads();
    }
    unsigned ex = ts[t] - sum;
    unsigned hx[4];
    for (int k = 0; k < 4; ++k) { hx[k] = ex; ex += v0[k]; }
    for (int k = 0; k < 4; ++k) {
        int idx = b * 1024 + t * 4 + k;
        if (idx < n) rp[idx] = s + hx[k];
        h[t * 4 + k] = hx[k];
    }
    if (b == nb - 1 && t == 0) rp[n] = eend;
    __syncthreads();
    for (unsigned i = s + t; i < eend; i += 256) {
        unsigned u = ent[i];
        unsigned p = s + atomicAdd(&h[u & 1023u], 1u);
        srcs[p] = u >> 10;
    }
}

// v-view localsort: per 256-variable bucket, counting sort by (v&255)<<2|chunk.
// rp written NODE-MAJOR: rp[node*4 + chunk]; rp[i*4+4] is node i+1's row start,
// so (start,end) of any (node,chunk) segment are adjacent words.
__global__ __launch_bounds__(256) void localsort_v_kernel(
    const unsigned* __restrict__ ent, const unsigned* __restrict__ base,
    int nb, int nv, unsigned* __restrict__ srcs, unsigned* __restrict__ rp) {
    __shared__ unsigned h[1024];
    __shared__ unsigned ts[256];
    int b = blockIdx.x, t = threadIdx.x;
    unsigned s = base[b], eend = base[b + 1];
    for (int k = 0; k < 4; ++k) h[t * 4 + k] = 0u;
    __syncthreads();
    for (unsigned i = s + t; i < eend; i += 256)
        atomicAdd(&h[ent[i] & 1023u], 1u);
    __syncthreads();
    unsigned v0[4];
    unsigned sum = 0;
    for (int k = 0; k < 4; ++k) { v0[k] = h[t * 4 + k]; sum += v0[k]; }
    ts[t] = sum;
    __syncthreads();
    for (int off = 1; off < 256; off <<= 1) {
        unsigned x = (t >= off) ? ts[t - off] : 0u;
        __syncthreads();
        ts[t] += x;
        __syncthreads();
    }
    unsigned ex = ts[t] - sum;
    unsigned hx[4];
    for (int k = 0; k < 4; ++k) { hx[k] = ex; ex += v0[k]; }
    int node = b * 256 + t;
    if (node < nv) {
        for (int k = 0; k < 4; ++k) rp[(size_t)node * 4 + k] = s + hx[k];
    }
    if (b == nb - 1 && t == 0) rp[(size_t)nv * 4] = eend;
    for (int k = 0; k < 4; ++k) h[t * 4 + k] = hx[k];
    __syncthreads();
    for (unsigned i = s + t; i < eend; i += 256) {
        unsigned u = ent[i];
        unsigned p = s + atomicAdd(&h[u & 1023u], 1u);
        srcs[p] = u >> 10;
    }
}

// ---------------- node init ----------------

__global__ void init_c_kernel(const float* __restrict__ x, const float* __restrict__ deg,
                              const float* __restrict__ W0, const float* __restrict__ b0,
                              float2* __restrict__ xc, unsigned* __restrict__ yc, int n) {
    int i = blockIdx.x * blockDim.x + threadIdx.x;
    if (i >= n) return;
    float xi = x[i];
    float2 o = make_float2(fmaf(xi, W0[0], b0[0]), fmaf(xi, W0[1], b0[1]));
    xc[i] = o;
    float d = deg[i];
    float inv = (d > 0.f) ? rsqrtf(d) : 0.f;
    yc[i] = packy(inv * o.x, inv * o.y);
}

__global__ void init_v_kernel(const float* __restrict__ x, const float* __restrict__ deg,
                              const float* __restrict__ W0, const float* __restrict__ b0,
                              float2* __restrict__ xv, unsigned* __restrict__ yv, int n) {
    int i = blockIdx.x * blockDim.x + threadIdx.x;
    if (i >= n) return;
    float xi = x[i];
    float2 o = make_float2(fmaf(xi, W0[0], b0[0]), fmaf(xi, W0[1], b0[1]));
    xv[i] = o;
    float d = deg[i];
    float inv = (d > 0.f) ? rsqrtf(d) : 0.f;
    yv[i] = packy(inv * o.x, inv * o.y);
}

// ---------------- per-layer kernels (no LDS, no atomics) ----------------

// One clause-chunk pass; gathers stay inside a 2MB window of yc (L2-resident).
// rp node-major: segment = [rp[i*4+k], rp[i*4+k+1]) for k=0..3.
__global__ __launch_bounds__(256) void v_chunk_pass(
    const unsigned* __restrict__ rp_p, const unsigned* __restrict__ src_p,
    const unsigned* __restrict__ rp_n, const unsigned* __restrict__ src_n,
    const unsigned* __restrict__ yc, float4* __restrict__ acc, int nv, int k) {
    int i = blockIdx.x * blockDim.x + threadIdx.x;
    if (i >= nv) return;
    float4 a = (k == 0) ? make_float4(0.f, 0.f, 0.f, 0.f) : acc[i];
    unsigned s0 = rp_p[(size_t)i * 4 + k], e0 = rp_p[(size_t)i * 4 + k + 1];
    for (unsigned j = s0; j < e0; ++j) {
        unsigned yw = yc[src_p[j]];
        a.x += bf_lo(yw); a.y += bf_hi(yw);
    }
    unsigned s1 = rp_n[(size_t)i * 4 + k], e1 = rp_n[(size_t)i * 4 + k + 1];
    for (unsigned j = s1; j < e1; ++j) {
        unsigned yw = yc[src_n[j]];
        a.z += bf_lo(yw); a.w += bf_hi(yw);
    }
    acc[i] = a;
}

__global__ __launch_bounds__(256) void v_finish_kernel(
    const float4* __restrict__ acc, const unsigned* __restrict__ rp_p,
    const unsigned* __restrict__ rp_n, float2* __restrict__ xv,
    const float* __restrict__ deg_v, const float* __restrict__ W,
    const float* __restrict__ bias, unsigned* __restrict__ yv_out, int nv, int writeY) {
    int i = blockIdx.x * blockDim.x + threadIdx.x;
    if (i >= nv) return;
    float4 a = acc[i];
    float cp = (float)(rp_p[(size_t)(i + 1) * 4] - rp_p[(size_t)i * 4]);
    float cn = (float)(rp_n[(size_t)(i + 1) * 4] - rp_n[(size_t)i * 4]);
    float2 xi = xv[i];
    float dv = deg_v[i];
    float iv = (dv > 0.f) ? rsqrtf(dv) : 0.f;
    float m0 = fmaf(iv, a.x, cp * xi.x);
    float m1 = fmaf(iv, a.y, cp * xi.y);
    float m2 = fmaf(iv, a.z, cn * xi.x);
    float m3 = fmaf(iv, a.w, cn * xi.y);
    float o0 = bias[0] + m0 * W[0] + m1 * W[2] + m2 * W[4] + m3 * W[6] + xi.x * W[8] + xi.y * W[10];
    float o1 = bias[1] + m0 * W[1] + m1 * W[3] + m2 * W[5] + m3 * W[7] + xi.x * W[9] + xi.y * W[11];
    xv[i] = make_float2(o0, o1);
    if (writeY) yv_out[i] = packy(iv * o0, iv * o1);
}

__global__ __launch_bounds__(256) void c_layer_csr(
    const unsigned* __restrict__ rp_p, const unsigned* __restrict__ src_p,
    const unsigned* __restrict__ rp_n, const unsigned* __restrict__ src_n,
    const unsigned* __restrict__ yv, float2* __restrict__ xc,
    const float* __restrict__ deg_c, unsigned* __restrict__ yc,
    const float* __restrict__ W, const float* __restrict__ bias, int nc) {
    int i = blockIdx.x * blockDim.x + threadIdx.x;
    if (i >= nc) return;
    unsigned s0 = rp_p[i], e0 = rp_p[i + 1];
    unsigned s1 = rp_n[i], e1 = rp_n[i + 1];
    float ax = 0.f, ay = 0.f, bx = 0.f, by = 0.f;
    for (unsigned j = s0; j < e0; ++j) {
        unsigned yw = yv[src_p[j]];
        ax += bf_lo(yw); ay += bf_hi(yw);
    }
    for (unsigned j = s1; j < e1; ++j) {
        unsigned yw = yv[src_n[j]];
        bx += bf_lo(yw); by += bf_hi(yw);
    }
    float cp = (float)(e0 - s0), cn = (float)(e1 - s1);
    float2 xi = xc[i];
    float dc = deg_c[i];
    float ic = (dc > 0.f) ? rsqrtf(dc) : 0.f;
    float m0 = fmaf(ic, ax, cp * xi.x);
    float m1 = fmaf(ic, ay, cp * xi.y);
    float m2 = fmaf(ic, bx, cn * xi.x);
    float m3 = fmaf(ic, by, cn * xi.y);
    float o0 = bias[0] + m0 * W[0] + m1 * W[2] + m2 * W[4] + m3 * W[6] + xi.x * W[8] + xi.y * W[10];
    float o1 = bias[1] + m0 * W[1] + m1 * W[3] + m2 * W[5] + m3 * W[7] + xi.x * W[9] + xi.y * W[11];
    xc[i] = make_float2(o0, o1);
    yc[i] = packy(ic * o0, ic * o1);
}

// ---------------- fallback: global-atomic path ----------------

__global__ void init_nodes(const float* __restrict__ x, const float* __restrict__ deg,
                           const float* __restrict__ W0, const float* __restrict__ b0,
                           float2* __restrict__ xf, float* __restrict__ inv, int n) {
    int i = blockIdx.x * blockDim.x + threadIdx.x;
    if (i >= n) return;
    float xi = x[i];
    xf[i] = make_float2(fmaf(xi, W0[0], b0[0]), fmaf(xi, W0[1], b0[1]));
    float d = deg[i];
    inv[i] = (d > 0.0f) ? (1.0f / sqrtf(d)) : 0.0f;
}

__global__ void count_edges(const int* __restrict__ src, const int* __restrict__ trg,
                            float* __restrict__ cnt_src, float* __restrict__ cnt_trg, int e) {
    int i = blockIdx.x * blockDim.x + threadIdx.x;
    if (i >= e) return;
    atomicAdd(&cnt_src[src[i]], 1.0f);
    atomicAdd(&cnt_trg[trg[i]], 1.0f);
}

__global__ void edge_pass(const int* __restrict__ src, const int* __restrict__ trg,
                          const float2* __restrict__ xc, const float2* __restrict__ xv,
                          const float* __restrict__ inv_c, const float* __restrict__ inv_v,
                          float2* __restrict__ Sv, float2* __restrict__ Sc, int e) {
    int i = blockIdx.x * blockDim.x + threadIdx.x;
    if (i >= e) return;
    int c = src[i];
    int v = trg[i];
    float ic = inv_c[c], iv = inv_v[v];
    float2 a = xc[c];
    float2 b = xv[v];
    atomicAdd(&Sv[v].x, a.x * ic);
    atomicAdd(&Sv[v].y, a.y * ic);
    atomicAdd(&Sc[c].x, b.x * iv);
    atomicAdd(&Sc[c].y, b.y * iv);
}

__global__ void node_update(float2* __restrict__ x, const float2* __restrict__ Sp,
                            const float2* __restrict__ Sn, const float* __restrict__ inv,
                            const float* __restrict__ cp, const float* __restrict__ cn,
                            const float* __restrict__ W, const float* __restrict__ b, int n) {
    int i = blockIdx.x * blockDim.x + threadIdx.x;
    if (i >= n) return;
    float2 xi = x[i];
    float ii = inv[i];
    float2 sp = Sp[i], sn = Sn[i];
    float cpi = cp[i], cni = cn[i];
    float m0 = fmaf(ii, sp.x, cpi * xi.x);
    float m1 = fmaf(ii, sp.y, cpi * xi.y);
    float m2 = fmaf(ii, sn.x, cni * xi.x);
    float m3 = fmaf(ii, sn.y, cni * xi.y);
    float o0 = b[0] + m0 * W[0] + m1 * W[2] + m2 * W[4] + m3 * W[6] + xi.x * W[8] + xi.y * W[10];
    float o1 = b[1] + m0 * W[1] + m1 * W[3] + m2 * W[5] + m3 * W[7] + xi.x * W[9] + xi.y * W[11];
    x[i] = make_float2(o0, o1);
}

// ---------------- launch ----------------

extern "C" void kernel_launch(void* const* d_in, const int* in_sizes, int n_in,
                              void* d_out, int out_size, void* d_ws, size_t ws_size,
                              hipStream_t stream) {
    const float* x_clause   = (const float*)d_in[0];
    const float* x_variable = (const float*)d_in[1];
    const float* deg_clause = (const float*)d_in[2];
    const float* deg_var    = (const float*)d_in[3];
    const int*   pos_src    = (const int*)d_in[4];
    const int*   pos_trg    = (const int*)d_in[5];
    const int*   neg_src    = (const int*)d_in[6];
    const int*   neg_trg    = (const int*)d_in[7];
    const float* W0c        = (const float*)d_in[8];
    const float* b0c        = (const float*)d_in[9];
    const float* W0v        = (const float*)d_in[10];
    const float* b0v        = (const float*)d_in[11];
    const float* Wc         = (const float*)d_in[12];
    const float* bc         = (const float*)d_in[13];
    const float* Wv         = (const float*)d_in[14];
    const float* bv         = (const float*)d_in[15];

    const int nc = in_sizes[0];
    const int nv = in_sizes[1];
    const int e  = in_sizes[4];
    const int B = 256;

    const int NBV = cdiv_h(nv, 256);
    const int NBC = cdiv_h(nc, 1024);
    const int maxnb = NBV > NBC ? NBV : NBC;
    const bool pack_ok = (NBV <= 2040) && (NBC <= 2040) && (nc <= (1 << 21)) && (nv <= (1 << 21));

    int cs = 0;  // clause-chunk shift: 4 chunks cover nc
    while ((4LL << cs) < nc) cs++;

    // -------- tier-1 layout: persistent arrays + build/layer overlay --------
    {
        size_t off = 0;
        auto alloc = [&](size_t bytes) {
            void* p = (char*)d_ws + off;
            off += (bytes + 255) & ~(size_t)255;
            return p;
        };
        unsigned* srcs_vp = (unsigned*)alloc((size_t)e * 4);
        unsigned* srcs_vn = (unsigned*)alloc((size_t)e * 4);
        unsigned* srcs_cp = (unsigned*)alloc((size_t)e * 4);
        unsigned* srcs_cn = (unsigned*)alloc((size_t)e * 4);
        unsigned* rp_vp   = (unsigned*)alloc((size_t)4 * (nv + 1) * 4);  // node-major [node*4+chunk]
        unsigned* rp_vn   = (unsigned*)alloc((size_t)4 * (nv + 1) * 4);
        unsigned* rp_cp   = (unsigned*)alloc((size_t)(nc + 1) * 4);
        unsigned* rp_cn   = (unsigned*)alloc((size_t)(nc + 1) * 4);
        const size_t overlay = off;
        // build-time view
        unsigned* temp    = (unsigned*)alloc((size_t)e * 4);
        unsigned* hist    = (unsigned*)alloc((size_t)maxnb * GAB * 4);
        unsigned* rowscan = (unsigned*)alloc((size_t)maxnb * GAB * 4);
        unsigned* row_tot = (unsigned*)alloc((size_t)maxnb * 4);
        unsigned* baseb   = (unsigned*)alloc((size_t)(maxnb + 1) * 4);
        const size_t build_end = off;
        // layer-time view (overlaps build scratch; inits run AFTER build)
        off = overlay;
        float4*   accv    = (float4*)alloc((size_t)nv * 16);
        float2*   xc      = (float2*)alloc((size_t)nc * 8);
        unsigned* yc      = (unsigned*)alloc((size_t)nc * 4);
        unsigned* yv      = (unsigned*)alloc((size_t)nv * 4);
        const size_t layer_end = off;
        const size_t required = build_end > layer_end ? build_end : layer_end;

        if (required <= ws_size && pack_ok) {
            const int chunk = cdiv_h(e, GAB);
            // v-views (bucket by v>>8, localsort by (v&255)<<2|clause_chunk)
            const int* vkeys[2] = { pos_trg, neg_trg };
            const int* vpays[2] = { pos_src, neg_src };
            unsigned* vsrcs[2] = { srcs_vp, srcs_vn };
            unsigned* vrps[2]  = { rp_vp, rp_vn };
            for (int p = 0; p < 2; ++p) {
                hist_kernel<<<GAB, BB, (size_t)NBV * 4, stream>>>(vkeys[p], e, chunk, 8, NBV, hist);
                rowscan256<<<NBV, B, 0, stream>>>(hist, rowscan, row_tot);
                basescan_kernel<<<1, 1024, 0, stream>>>(row_tot, baseb, NBV);
                scatter_v_kernel<<<GAB, BB, (size_t)NBV * 4, stream>>>(vkeys[p], vpays[p], e, chunk,
                                                                       cs, NBV, rowscan, baseb, temp);
                localsort_v_kernel<<<NBV, B, 0, stream>>>(temp, baseb, NBV, nv, vsrcs[p], vrps[p]);
            }
            // c-views (bucket by c>>10, localsort by c&1023)
            const int* ckeys[2] = { pos_src, neg_src };
            const int* cpays[2] = { pos_trg, neg_trg };
            unsigned* csrcs[2] = { srcs_cp, srcs_cn };
            unsigned* crps[2]  = { rp_cp, rp_cn };
            for (int p = 0; p < 2; ++p) {
                hist_kernel<<<GAB, BB, (size_t)NBC * 4, stream>>>(ckeys[p], e, chunk, 10, NBC, hist);
                rowscan256<<<NBC, B, 0, stream>>>(hist, rowscan, row_tot);
                basescan_kernel<<<1, 1024, 0, stream>>>(row_tot, baseb, NBC);
                scatter_kernel<<<GAB, BB, (size_t)NBC * 4, stream>>>(ckeys[p], cpays[p], e, chunk,
                                                                     10, 1023, NBC, rowscan, baseb, temp);
                localsort_c_kernel<<<NBC, B, 0, stream>>>(temp, baseb, NBC, nc, csrcs[p], crps[p]);
            }

            float2* xv = (float2*)d_out;  // updated in place each layer
            init_c_kernel<<<cdiv_h(nc, B), B, 0, stream>>>(x_clause, deg_clause, W0c, b0c, xc, yc, nc);
            init_v_kernel<<<cdiv_h(nv, B), B, 0, stream>>>(x_variable, deg_var, W0v, b0v, xv, yv, nv);

            for (int l = 0; l < 4; ++l) {
                for (int k = 0; k < 4; ++k) {
                    v_chunk_pass<<<cdiv_h(nv, B), B, 0, stream>>>(rp_vp, srcs_vp, rp_vn, srcs_vn,
                                                                  yc, accv, nv, k);
                }
                if (l < 3) {
                    // reads yv (= y of xv_l, untouched so far this layer), rewrites xc/yc
                    c_layer_csr<<<cdiv_h(nc, B), B, 0, stream>>>(rp_cp, srcs_cp, rp_cn, srcs_cn,
                                                                 yv, xc, deg_clause, yc,
                                                                 Wc + l * 12, bc + l * 2, nc);
                }
                // in-place xv update; writes yv for the NEXT layer's c_layer (only needed l<2)
                v_finish_kernel<<<cdiv_h(nv, B), B, 0, stream>>>(accv, rp_vp, rp_vn, xv, deg_var,
                                                                 Wv + l * 12, bv + l * 2, yv, nv,
                                                                 (l < 2) ? 1 : 0);
            }
            return;
        }
    }

    // -------- fallback: global-atomic path --------
    char* p = (char*)d_ws;
    float2* Sv_pos = (float2*)p; p += (size_t)nv * sizeof(float2);
    float2* Sv_neg = (float2*)p; p += (size_t)nv * sizeof(float2);
    float2* Sc_pos = (float2*)p; p += (size_t)nc * sizeof(float2);
    float2* Sc_neg = (float2*)p; p += (size_t)nc * sizeof(float2);
    const size_t s_bytes = (size_t)(2 * nv + 2 * nc) * sizeof(float2);
    float2* xc2 = (float2*)p; p += (size_t)nc * sizeof(float2);
    float* inv_c = (float*)p; p += (size_t)nc * sizeof(float);
    float* inv_v = (float*)p; p += (size_t)nv * sizeof(float);
    float* cntc_pos = (float*)p; p += (size_t)nc * sizeof(float);
    float* cntc_neg = (float*)p; p += (size_t)nc * sizeof(float);
    float* cntv_pos = (float*)p; p += (size_t)nv * sizeof(float);
    float* cntv_neg = (float*)p; p += (size_t)nv * sizeof(float);
    const size_t cnt_bytes = (size_t)(2 * nc + 2 * nv) * sizeof(float);
    float2* xv = (float2*)d_out;

    hipMemsetAsync(Sv_pos, 0, s_bytes, stream);
    hipMemsetAsync(cntc_pos, 0, cnt_bytes, stream);
    init_nodes<<<cdiv_h(nc, B), B, 0, stream>>>(x_clause, deg_clause, W0c, b0c, xc2, inv_c, nc);
    init_nodes<<<cdiv_h(nv, B), B, 0, stream>>>(x_variable, deg_var, W0v, b0v, xv, inv_v, nv);
    count_edges<<<cdiv_h(e, B), B, 0, stream>>>(pos_src, pos_trg, cntc_pos, cntv_pos, e);
    count_edges<<<cdiv_h(e, B), B, 0, stream>>>(neg_src, neg_trg, cntc_neg, cntv_neg, e);
    for (int l = 0; l < 4; ++l) {
        edge_pass<<<cdiv_h(e, B), B, 0, stream>>>(pos_src, pos_trg, xc2, xv, inv_c, inv_v,
                                                  Sv_pos, Sc_pos, e);
        edge_pass<<<cdiv_h(e, B), B, 0, stream>>>(neg_src, neg_trg, xc2, xv, inv_c, inv_v,
                                                  Sv_neg, Sc_neg, e);
        node_update<<<cdiv_h(nv, B), B, 0, stream>>>(xv, Sv_pos, Sv_neg, inv_v,
                                                     cntv_pos, cntv_neg, Wv + l * 12, bv + l * 2, nv);
        node_update<<<cdiv_h(nc, B), B, 0, stream>>>(xc2, Sc_pos, Sc_neg, inv_c,
                                                     cntc_pos, cntc_neg, Wc + l * 12, bc + l * 2, nc);
        if (l < 3) hipMemsetAsync(Sv_pos, 0, s_bytes, stream);
    }
}

// Round 7
// 1306.698 us; speedup vs baseline: 1.5005x; 1.0517x over previous
//
#include <hip/hip_runtime.h>

// G4GCN: 4-layer linear bipartite GNN (clauses <-> variables), feature dim 2.
//
// Round-6 lesson: bucket scatter was bound by WRITE amplification (150MB HBM
// writes for 24MB logical: ~1954 open runs/block over a 24MB span -> lines
// evicted part-filled). Occupancy was NOT the issue (9.5%->37% gave only -6%).
// Round-7 build: two-level partition.
//   pass1: coarse scatter into ~245 super-buckets (runs ~96 words/block,
//          open-line set ~512KB/XCD -> L2-resident, ~1x write amp).
//   pass2: one 1024-thread block per SB: LDS counting sort (8192 counters)
//          producing final CSR; scatter writes confined to the SB's ~94KB
//          output window (L2-local). Absorbs the old fine scatter.
// Packing: v-view entry (c<<11)|(v&2047) [21+11b]; c-view (v<<13)|(c&8191)
// [19+13b]. Layer kernels unchanged (L2-chunked v gathers, CSR, no atomics).

#define GAB 256   // blocks for build hist/scatter passes
#define BB  1024  // threads for build hist/scatter passes

static inline int cdiv_h(long long a, long long b) { return (int)((a + b - 1) / b); }

__device__ inline float bf_lo(unsigned u) { return __uint_as_float(u << 16); }
__device__ inline float bf_hi(unsigned u) { return __uint_as_float(u & 0xffff0000u); }
__device__ inline unsigned packy(float a, float b) {
    unsigned ua = __float_as_uint(a), ub = __float_as_uint(b);
    ua = (ua + 0x7fffu + ((ua >> 16) & 1u)) >> 16;
    ub = (ub + 0x7fffu + ((ub >> 16) & 1u)) & 0xffff0000u;
    return ua | ub;
}

// ---------------- build: coarse counting partition ----------------

// 4-way replicated LDS histogram (bins are few -> contention without it)
__global__ __launch_bounds__(BB) void hist_kernel(
    const int* __restrict__ key, int e, int chunk, int shift,
    int nb, unsigned* __restrict__ hist /*[nb][GAB]*/) {
    extern __shared__ unsigned h[];  // nb*4
    int blk = blockIdx.x, tid = threadIdx.x;
    for (int i = tid; i < nb * 4; i += blockDim.x) h[i] = 0u;
    __syncthreads();
    int s = blk * chunk, epos = min(e, s + chunk);
    int r = tid & 3;
    for (int i = s + tid; i < epos; i += blockDim.x)
        atomicAdd(&h[(((unsigned)(key[i] >> shift)) << 2) | r], 1u);
    __syncthreads();
    for (int i = tid; i < nb; i += blockDim.x)
        hist[(size_t)i * GAB + blk] = h[4 * i] + h[4 * i + 1] + h[4 * i + 2] + h[4 * i + 3];
}

__global__ void rowscan256(const unsigned* __restrict__ hist, unsigned* __restrict__ rowscan,
                           unsigned* __restrict__ row_total) {
    __shared__ unsigned ts[256];
    int b = blockIdx.x, t = threadIdx.x;
    unsigned v0 = hist[(size_t)b * GAB + t];
    ts[t] = v0;
    __syncthreads();
    for (int off = 1; off < 256; off <<= 1) {
        unsigned v = (t >= off) ? ts[t - off] : 0u;
        __syncthreads();
        ts[t] += v;
        __syncthreads();
    }
    rowscan[(size_t)b * GAB + t] = ts[t] - v0;
    if (t == 255) row_total[b] = ts[255];
}

__global__ void basescan_kernel(const unsigned* __restrict__ row_total,
                                unsigned* __restrict__ base, int nb) {
    __shared__ unsigned a[2048];
    __shared__ unsigned ts[1024];
    int t = threadIdx.x;
    a[t] = (t < nb) ? row_total[t] : 0u;
    a[t + 1024] = (t + 1024 < nb) ? row_total[t + 1024] : 0u;
    __syncthreads();
    unsigned a0 = a[2 * t], a1 = a[2 * t + 1];
    unsigned sum = a0 + a1;
    ts[t] = sum;
    __syncthreads();
    for (int off = 1; off < 1024; off <<= 1) {
        unsigned v = (t >= off) ? ts[t - off] : 0u;
        __syncthreads();
        ts[t] += v;
        __syncthreads();
    }
    unsigned b0 = ts[t] - sum;
    if (2 * t <= nb) base[2 * t] = b0;
    if (2 * t + 1 <= nb) base[2 * t + 1] = b0 + a0;
}

// coarse scatter: bucket by key>>kshift; entry = (pay << kshift) | (key & mask)
__global__ __launch_bounds__(BB) void scatter_sb(
    const int* __restrict__ key, const int* __restrict__ pay,
    int e, int chunk, int kshift, int nb,
    const unsigned* __restrict__ rowscan, const unsigned* __restrict__ base,
    unsigned* __restrict__ out) {
    extern __shared__ unsigned cur[];
    int blk = blockIdx.x, tid = threadIdx.x;
    for (int i = tid; i < nb; i += blockDim.x)
        cur[i] = base[i] + rowscan[(size_t)i * GAB + blk];
    __syncthreads();
    int s = blk * chunk, epos = min(e, s + chunk);
    unsigned mask = (1u << kshift) - 1u;
    for (int i = s + tid; i < epos; i += blockDim.x) {
        int k = key[i];
        int b = k >> kshift;
        unsigned p = atomicAdd(&cur[b], 1u);
        out[p] = ((unsigned)pay[i] << kshift) | ((unsigned)k & mask);
    }
}

// v-view SB localsort: block per 2048-variable super-bucket.
// entry = (c<<11)|(v&2047); key = (v&2047)<<2 | chunk(c); 8192 LDS counters.
// rp node-major rp[node*4+chunk]; srcs[p] = full clause id.
__global__ __launch_bounds__(1024) void localsort_v_sb(
    const unsigned* __restrict__ ent, const unsigned* __restrict__ base,
    int nsb, int nv, int cs, unsigned* __restrict__ srcs, unsigned* __restrict__ rp) {
    __shared__ unsigned h[8192];
    __shared__ unsigned ts[1024];
    int s = blockIdx.x, t = threadIdx.x;
    unsigned sb = base[s], se = base[s + 1];
    for (int k = 0; k < 8; ++k) h[t * 8 + k] = 0u;
    __syncthreads();
    for (unsigned i = sb + t; i < se; i += 1024) {
        unsigned u = ent[i];
        unsigned c = u >> 11;
        atomicAdd(&h[((u & 2047u) << 2) | (c >> cs)], 1u);
    }
    __syncthreads();
    unsigned v0[8];
    unsigned sum = 0;
    for (int k = 0; k < 8; ++k) { v0[k] = h[t * 8 + k]; sum += v0[k]; }
    ts[t] = sum;
    __syncthreads();
    for (int off = 1; off < 1024; off <<= 1) {
        unsigned x = (t >= off) ? ts[t - off] : 0u;
        __syncthreads();
        ts[t] += x;
        __syncthreads();
    }
    unsigned ex = ts[t] - sum;
    unsigned hx[8];
    for (int k = 0; k < 8; ++k) { hx[k] = ex; ex += v0[k]; }
    int node0 = s * 2048 + t * 2;  // keys t*8..t*8+7 = nodes t*2,t*2+1 x 4 chunks
    for (int j = 0; j < 2; ++j) {
        int node = node0 + j;
        if (node < nv)
            for (int ch = 0; ch < 4; ++ch)
                rp[(size_t)node * 4 + ch] = sb + hx[j * 4 + ch];
    }
    if (s == nsb - 1 && t == 0) rp[(size_t)nv * 4] = se;
    for (int k = 0; k < 8; ++k) h[t * 8 + k] = hx[k];
    __syncthreads();
    for (unsigned i = sb + t; i < se; i += 1024) {
        unsigned u = ent[i];
        unsigned c = u >> 11;
        unsigned p = sb + atomicAdd(&h[((u & 2047u) << 2) | (c >> cs)], 1u);
        srcs[p] = c;
    }
}

// c-view SB localsort: block per 8192-clause super-bucket.
// entry = (v<<13)|(c&8191); key = c&8191; linear rp[nc+1]; srcs[p] = variable id.
__global__ __launch_bounds__(1024) void localsort_c_sb(
    const unsigned* __restrict__ ent, const unsigned* __restrict__ base,
    int nsb, int nc, unsigned* __restrict__ srcs, unsigned* __restrict__ rp) {
    __shared__ unsigned h[8192];
    __shared__ unsigned ts[1024];
    int s = blockIdx.x, t = threadIdx.x;
    unsigned sb = base[s], se = base[s + 1];
    for (int k = 0; k < 8; ++k) h[t * 8 + k] = 0u;
    __syncthreads();
    for (unsigned i = sb + t; i < se; i += 1024)
        atomicAdd(&h[ent[i] & 8191u], 1u);
    __syncthreads();
    unsigned v0[8];
    unsigned sum = 0;
    for (int k = 0; k < 8; ++k) { v0[k] = h[t * 8 + k]; sum += v0[k]; }
    ts[t] = sum;
    __syncthreads();
    for (int off = 1; off < 1024; off <<= 1) {
        unsigned x = (t >= off) ? ts[t - off] : 0u;
        __syncthreads();
        ts[t] += x;
        __syncthreads();
    }
    unsigned ex = ts[t] - sum;
    unsigned hx[8];
    for (int k = 0; k < 8; ++k) { hx[k] = ex; ex += v0[k]; }
    int node0 = s * 8192 + t * 8;
    for (int k = 0; k < 8; ++k) {
        int node = node0 + k;
        if (node < nc) rp[node] = sb + hx[k];
    }
    if (s == nsb - 1 && t == 0) rp[nc] = se;
    for (int k = 0; k < 8; ++k) h[t * 8 + k] = hx[k];
    __syncthreads();
    for (unsigned i = sb + t; i < se; i += 1024) {
        unsigned u = ent[i];
        unsigned p = sb + atomicAdd(&h[u & 8191u], 1u);
        srcs[p] = u >> 13;
    }
}

// ---------------- node init ----------------

__global__ void init_c_kernel(const float* __restrict__ x, const float* __restrict__ deg,
                              const float* __restrict__ W0, const float* __restrict__ b0,
                              float2* __restrict__ xc, unsigned* __restrict__ yc, int n) {
    int i = blockIdx.x * blockDim.x + threadIdx.x;
    if (i >= n) return;
    float xi = x[i];
    float2 o = make_float2(fmaf(xi, W0[0], b0[0]), fmaf(xi, W0[1], b0[1]));
    xc[i] = o;
    float d = deg[i];
    float inv = (d > 0.f) ? rsqrtf(d) : 0.f;
    yc[i] = packy(inv * o.x, inv * o.y);
}

__global__ void init_v_kernel(const float* __restrict__ x, const float* __restrict__ deg,
                              const float* __restrict__ W0, const float* __restrict__ b0,
                              float2* __restrict__ xv, unsigned* __restrict__ yv, int n) {
    int i = blockIdx.x * blockDim.x + threadIdx.x;
    if (i >= n) return;
    float xi = x[i];
    float2 o = make_float2(fmaf(xi, W0[0], b0[0]), fmaf(xi, W0[1], b0[1]));
    xv[i] = o;
    float d = deg[i];
    float inv = (d > 0.f) ? rsqrtf(d) : 0.f;
    yv[i] = packy(inv * o.x, inv * o.y);
}

// ---------------- per-layer kernels (no LDS, no atomics) ----------------

__global__ __launch_bounds__(256) void v_chunk_pass(
    const unsigned* __restrict__ rp_p, const unsigned* __restrict__ src_p,
    const unsigned* __restrict__ rp_n, const unsigned* __restrict__ src_n,
    const unsigned* __restrict__ yc, float4* __restrict__ acc, int nv, int k) {
    int i = blockIdx.x * blockDim.x + threadIdx.x;
    if (i >= nv) return;
    float4 a = (k == 0) ? make_float4(0.f, 0.f, 0.f, 0.f) : acc[i];
    unsigned s0 = rp_p[(size_t)i * 4 + k], e0 = rp_p[(size_t)i * 4 + k + 1];
    for (unsigned j = s0; j < e0; ++j) {
        unsigned yw = yc[src_p[j]];
        a.x += bf_lo(yw); a.y += bf_hi(yw);
    }
    unsigned s1 = rp_n[(size_t)i * 4 + k], e1 = rp_n[(size_t)i * 4 + k + 1];
    for (unsigned j = s1; j < e1; ++j) {
        unsigned yw = yc[src_n[j]];
        a.z += bf_lo(yw); a.w += bf_hi(yw);
    }
    acc[i] = a;
}

__global__ __launch_bounds__(256) void v_finish_kernel(
    const float4* __restrict__ acc, const unsigned* __restrict__ rp_p,
    const unsigned* __restrict__ rp_n, float2* __restrict__ xv,
    const float* __restrict__ deg_v, const float* __restrict__ W,
    const float* __restrict__ bias, unsigned* __restrict__ yv_out, int nv, int writeY) {
    int i = blockIdx.x * blockDim.x + threadIdx.x;
    if (i >= nv) return;
    float4 a = acc[i];
    float cp = (float)(rp_p[(size_t)(i + 1) * 4] - rp_p[(size_t)i * 4]);
    float cn = (float)(rp_n[(size_t)(i + 1) * 4] - rp_n[(size_t)i * 4]);
    float2 xi = xv[i];
    float dv = deg_v[i];
    float iv = (dv > 0.f) ? rsqrtf(dv) : 0.f;
    float m0 = fmaf(iv, a.x, cp * xi.x);
    float m1 = fmaf(iv, a.y, cp * xi.y);
    float m2 = fmaf(iv, a.z, cn * xi.x);
    float m3 = fmaf(iv, a.w, cn * xi.y);
    float o0 = bias[0] + m0 * W[0] + m1 * W[2] + m2 * W[4] + m3 * W[6] + xi.x * W[8] + xi.y * W[10];
    float o1 = bias[1] + m0 * W[1] + m1 * W[3] + m2 * W[5] + m3 * W[7] + xi.x * W[9] + xi.y * W[11];
    xv[i] = make_float2(o0, o1);
    if (writeY) yv_out[i] = packy(iv * o0, iv * o1);
}

__global__ __launch_bounds__(256) void c_layer_csr(
    const unsigned* __restrict__ rp_p, const unsigned* __restrict__ src_p,
    const unsigned* __restrict__ rp_n, const unsigned* __restrict__ src_n,
    const unsigned* __restrict__ yv, float2* __restrict__ xc,
    const float* __restrict__ deg_c, unsigned* __restrict__ yc,
    const float* __restrict__ W, const float* __restrict__ bias, int nc) {
    int i = blockIdx.x * blockDim.x + threadIdx.x;
    if (i >= nc) return;
    unsigned s0 = rp_p[i], e0 = rp_p[i + 1];
    unsigned s1 = rp_n[i], e1 = rp_n[i + 1];
    float ax = 0.f, ay = 0.f, bx = 0.f, by = 0.f;
    for (unsigned j = s0; j < e0; ++j) {
        unsigned yw = yv[src_p[j]];
        ax += bf_lo(yw); ay += bf_hi(yw);
    }
    for (unsigned j = s1; j < e1; ++j) {
        unsigned yw = yv[src_n[j]];
        bx += bf_lo(yw); by += bf_hi(yw);
    }
    float cp = (float)(e0 - s0), cn = (float)(e1 - s1);
    float2 xi = xc[i];
    float dc = deg_c[i];
    float ic = (dc > 0.f) ? rsqrtf(dc) : 0.f;
    float m0 = fmaf(ic, ax, cp * xi.x);
    float m1 = fmaf(ic, ay, cp * xi.y);
    float m2 = fmaf(ic, bx, cn * xi.x);
    float m3 = fmaf(ic, by, cn * xi.y);
    float o0 = bias[0] + m0 * W[0] + m1 * W[2] + m2 * W[4] + m3 * W[6] + xi.x * W[8] + xi.y * W[10];
    float o1 = bias[1] + m0 * W[1] + m1 * W[3] + m2 * W[5] + m3 * W[7] + xi.x * W[9] + xi.y * W[11];
    xc[i] = make_float2(o0, o1);
    yc[i] = packy(ic * o0, ic * o1);
}

// ---------------- fallback: global-atomic path ----------------

__global__ void init_nodes(const float* __restrict__ x, const float* __restrict__ deg,
                           const float* __restrict__ W0, const float* __restrict__ b0,
                           float2* __restrict__ xf, float* __restrict__ inv, int n) {
    int i = blockIdx.x * blockDim.x + threadIdx.x;
    if (i >= n) return;
    float xi = x[i];
    xf[i] = make_float2(fmaf(xi, W0[0], b0[0]), fmaf(xi, W0[1], b0[1]));
    float d = deg[i];
    inv[i] = (d > 0.0f) ? (1.0f / sqrtf(d)) : 0.0f;
}

__global__ void count_edges(const int* __restrict__ src, const int* __restrict__ trg,
                            float* __restrict__ cnt_src, float* __restrict__ cnt_trg, int e) {
    int i = blockIdx.x * blockDim.x + threadIdx.x;
    if (i >= e) return;
    atomicAdd(&cnt_src[src[i]], 1.0f);
    atomicAdd(&cnt_trg[trg[i]], 1.0f);
}

__global__ void edge_pass(const int* __restrict__ src, const int* __restrict__ trg,
                          const float2* __restrict__ xc, const float2* __restrict__ xv,
                          const float* __restrict__ inv_c, const float* __restrict__ inv_v,
                          float2* __restrict__ Sv, float2* __restrict__ Sc, int e) {
    int i = blockIdx.x * blockDim.x + threadIdx.x;
    if (i >= e) return;
    int c = src[i];
    int v = trg[i];
    float ic = inv_c[c], iv = inv_v[v];
    float2 a = xc[c];
    float2 b = xv[v];
    atomicAdd(&Sv[v].x, a.x * ic);
    atomicAdd(&Sv[v].y, a.y * ic);
    atomicAdd(&Sc[c].x, b.x * iv);
    atomicAdd(&Sc[c].y, b.y * iv);
}

__global__ void node_update(float2* __restrict__ x, const float2* __restrict__ Sp,
                            const float2* __restrict__ Sn, const float* __restrict__ inv,
                            const float* __restrict__ cp, const float* __restrict__ cn,
                            const float* __restrict__ W, const float* __restrict__ b, int n) {
    int i = blockIdx.x * blockDim.x + threadIdx.x;
    if (i >= n) return;
    float2 xi = x[i];
    float ii = inv[i];
    float2 sp = Sp[i], sn = Sn[i];
    float cpi = cp[i], cni = cn[i];
    float m0 = fmaf(ii, sp.x, cpi * xi.x);
    float m1 = fmaf(ii, sp.y, cpi * xi.y);
    float m2 = fmaf(ii, sn.x, cni * xi.x);
    float m3 = fmaf(ii, sn.y, cni * xi.y);
    float o0 = b[0] + m0 * W[0] + m1 * W[2] + m2 * W[4] + m3 * W[6] + xi.x * W[8] + xi.y * W[10];
    float o1 = b[1] + m0 * W[1] + m1 * W[3] + m2 * W[5] + m3 * W[7] + xi.x * W[9] + xi.y * W[11];
    x[i] = make_float2(o0, o1);
}

// ---------------- launch ----------------

extern "C" void kernel_launch(void* const* d_in, const int* in_sizes, int n_in,
                              void* d_out, int out_size, void* d_ws, size_t ws_size,
                              hipStream_t stream) {
    const float* x_clause   = (const float*)d_in[0];
    const float* x_variable = (const float*)d_in[1];
    const float* deg_clause = (const float*)d_in[2];
    const float* deg_var    = (const float*)d_in[3];
    const int*   pos_src    = (const int*)d_in[4];
    const int*   pos_trg    = (const int*)d_in[5];
    const int*   neg_src    = (const int*)d_in[6];
    const int*   neg_trg    = (const int*)d_in[7];
    const float* W0c        = (const float*)d_in[8];
    const float* b0c        = (const float*)d_in[9];
    const float* W0v        = (const float*)d_in[10];
    const float* b0v        = (const float*)d_in[11];
    const float* Wc         = (const float*)d_in[12];
    const float* bc         = (const float*)d_in[13];
    const float* Wv         = (const float*)d_in[14];
    const float* bv         = (const float*)d_in[15];

    const int nc = in_sizes[0];
    const int nv = in_sizes[1];
    const int e  = in_sizes[4];
    const int B = 256;

    const int NSBV = cdiv_h(nv, 2048);   // v super-buckets (2048 vars each)
    const int NSBC = cdiv_h(nc, 8192);   // c super-buckets (8192 clauses each)
    const int maxnb = NSBV > NSBC ? NSBV : NSBC;
    const bool pack_ok = (nc <= (1 << 21)) && (nv <= (1 << 19));

    int cs = 0;  // clause-chunk shift: 4 chunks cover nc
    while ((4LL << cs) < nc) cs++;

    // -------- tier-1 layout: persistent arrays + build/layer overlay --------
    {
        size_t off = 0;
        auto alloc = [&](size_t bytes) {
            void* p = (char*)d_ws + off;
            off += (bytes + 255) & ~(size_t)255;
            return p;
        };
        unsigned* srcs_vp = (unsigned*)alloc((size_t)e * 4);
        unsigned* srcs_vn = (unsigned*)alloc((size_t)e * 4);
        unsigned* srcs_cp = (unsigned*)alloc((size_t)e * 4);
        unsigned* srcs_cn = (unsigned*)alloc((size_t)e * 4);
        unsigned* rp_vp   = (unsigned*)alloc((size_t)4 * (nv + 1) * 4);  // node-major [node*4+chunk]
        unsigned* rp_vn   = (unsigned*)alloc((size_t)4 * (nv + 1) * 4);
        unsigned* rp_cp   = (unsigned*)alloc((size_t)(nc + 1) * 4);
        unsigned* rp_cn   = (unsigned*)alloc((size_t)(nc + 1) * 4);
        const size_t overlay = off;
        // build-time view
        unsigned* temp    = (unsigned*)alloc((size_t)e * 4);
        unsigned* hist    = (unsigned*)alloc((size_t)maxnb * GAB * 4);
        unsigned* rowscan = (unsigned*)alloc((size_t)maxnb * GAB * 4);
        unsigned* row_tot = (unsigned*)alloc((size_t)maxnb * 4);
        unsigned* baseb   = (unsigned*)alloc((size_t)(maxnb + 1) * 4);
        const size_t build_end = off;
        // layer-time view (overlaps build scratch; inits run AFTER build)
        off = overlay;
        float4*   accv    = (float4*)alloc((size_t)nv * 16);
        float2*   xc      = (float2*)alloc((size_t)nc * 8);
        unsigned* yc      = (unsigned*)alloc((size_t)nc * 4);
        unsigned* yv      = (unsigned*)alloc((size_t)nv * 4);
        const size_t layer_end = off;
        const size_t required = build_end > layer_end ? build_end : layer_end;

        if (required <= ws_size && pack_ok) {
            const int chunk = cdiv_h(e, GAB);
            // v-views: coarse by v>>11, SB-localsort by (v&2047)<<2|chunk(c)
            const int* vkeys[2] = { pos_trg, neg_trg };
            const int* vpays[2] = { pos_src, neg_src };
            unsigned* vsrcs[2] = { srcs_vp, srcs_vn };
            unsigned* vrps[2]  = { rp_vp, rp_vn };
            for (int p = 0; p < 2; ++p) {
                hist_kernel<<<GAB, BB, (size_t)NSBV * 16, stream>>>(vkeys[p], e, chunk, 11, NSBV, hist);
                rowscan256<<<NSBV, B, 0, stream>>>(hist, rowscan, row_tot);
                basescan_kernel<<<1, 1024, 0, stream>>>(row_tot, baseb, NSBV);
                scatter_sb<<<GAB, BB, (size_t)NSBV * 4, stream>>>(vkeys[p], vpays[p], e, chunk,
                                                                  11, NSBV, rowscan, baseb, temp);
                localsort_v_sb<<<NSBV, 1024, 0, stream>>>(temp, baseb, NSBV, nv, cs,
                                                          vsrcs[p], vrps[p]);
            }
            // c-views: coarse by c>>13, SB-localsort by c&8191
            const int* ckeys[2] = { pos_src, neg_src };
            const int* cpays[2] = { pos_trg, neg_trg };
            unsigned* csrcs[2] = { srcs_cp, srcs_cn };
            unsigned* crps[2]  = { rp_cp, rp_cn };
            for (int p = 0; p < 2; ++p) {
                hist_kernel<<<GAB, BB, (size_t)NSBC * 16, stream>>>(ckeys[p], e, chunk, 13, NSBC, hist);
                rowscan256<<<NSBC, B, 0, stream>>>(hist, rowscan, row_tot);
                basescan_kernel<<<1, 1024, 0, stream>>>(row_tot, baseb, NSBC);
                scatter_sb<<<GAB, BB, (size_t)NSBC * 4, stream>>>(ckeys[p], cpays[p], e, chunk,
                                                                  13, NSBC, rowscan, baseb, temp);
                localsort_c_sb<<<NSBC, 1024, 0, stream>>>(temp, baseb, NSBC, nc,
                                                          csrcs[p], crps[p]);
            }

            float2* xv = (float2*)d_out;  // updated in place each layer
            init_c_kernel<<<cdiv_h(nc, B), B, 0, stream>>>(x_clause, deg_clause, W0c, b0c, xc, yc, nc);
            init_v_kernel<<<cdiv_h(nv, B), B, 0, stream>>>(x_variable, deg_var, W0v, b0v, xv, yv, nv);

            for (int l = 0; l < 4; ++l) {
                for (int k = 0; k < 4; ++k) {
                    v_chunk_pass<<<cdiv_h(nv, B), B, 0, stream>>>(rp_vp, srcs_vp, rp_vn, srcs_vn,
                                                                  yc, accv, nv, k);
                }
                if (l < 3) {
                    c_layer_csr<<<cdiv_h(nc, B), B, 0, stream>>>(rp_cp, srcs_cp, rp_cn, srcs_cn,
                                                                 yv, xc, deg_clause, yc,
                                                                 Wc + l * 12, bc + l * 2, nc);
                }
                v_finish_kernel<<<cdiv_h(nv, B), B, 0, stream>>>(accv, rp_vp, rp_vn, xv, deg_var,
                                                                 Wv + l * 12, bv + l * 2, yv, nv,
                                                                 (l < 2) ? 1 : 0);
            }
            return;
        }
    }

    // -------- fallback: global-atomic path --------
    char* p = (char*)d_ws;
    float2* Sv_pos = (float2*)p; p += (size_t)nv * sizeof(float2);
    float2* Sv_neg = (float2*)p; p += (size_t)nv * sizeof(float2);
    float2* Sc_pos = (float2*)p; p += (size_t)nc * sizeof(float2);
    float2* Sc_neg = (float2*)p; p += (size_t)nc * sizeof(float2);
    const size_t s_bytes = (size_t)(2 * nv + 2 * nc) * sizeof(float2);
    float2* xc2 = (float2*)p; p += (size_t)nc * sizeof(float2);
    float* inv_c = (float*)p; p += (size_t)nc * sizeof(float);
    float* inv_v = (float*)p; p += (size_t)nv * sizeof(float);
    float* cntc_pos = (float*)p; p += (size_t)nc * sizeof(float);
    float* cntc_neg = (float*)p; p += (size_t)nc * sizeof(float);
    float* cntv_pos = (float*)p; p += (size_t)nv * sizeof(float);
    float* cntv_neg = (float*)p; p += (size_t)nv * sizeof(float);
    const size_t cnt_bytes = (size_t)(2 * nc + 2 * nv) * sizeof(float);
    float2* xv = (float2*)d_out;

    hipMemsetAsync(Sv_pos, 0, s_bytes, stream);
    hipMemsetAsync(cntc_pos, 0, cnt_bytes, stream);
    init_nodes<<<cdiv_h(nc, B), B, 0, stream>>>(x_clause, deg_clause, W0c, b0c, xc2, inv_c, nc);
    init_nodes<<<cdiv_h(nv, B), B, 0, stream>>>(x_variable, deg_var, W0v, b0v, xv, inv_v, nv);
    count_edges<<<cdiv_h(e, B), B, 0, stream>>>(pos_src, pos_trg, cntc_pos, cntv_pos, e);
    count_edges<<<cdiv_h(e, B), B, 0, stream>>>(neg_src, neg_trg, cntc_neg, cntv_neg, e);
    for (int l = 0; l < 4; ++l) {
        edge_pass<<<cdiv_h(e, B), B, 0, stream>>>(pos_src, pos_trg, xc2, xv, inv_c, inv_v,
                                                  Sv_pos, Sc_pos, e);
        edge_pass<<<cdiv_h(e, B), B, 0, stream>>>(neg_src, neg_trg, xc2, xv, inv_c, inv_v,
                                                  Sv_neg, Sc_neg, e);
        node_update<<<cdiv_h(nv, B), B, 0, stream>>>(xv, Sv_pos, Sv_neg, inv_v,
                                                     cntv_pos, cntv_neg, Wv + l * 12, bv + l * 2, nv);
        node_update<<<cdiv_h(nc, B), B, 0, stream>>>(xc2, Sc_pos, Sc_neg, inv_c,
                                                     cntc_pos, cntc_neg, Wc + l * 12, bc + l * 2, nc);
        if (l < 3) hipMemsetAsync(Sv_pos, 0, s_bytes, stream);
    }
}

// Round 8
// 1169.553 us; speedup vs baseline: 1.6764x; 1.1173x over previous
//
#include <hip/hip_runtime.h>

// G4GCN: 4-layer linear bipartite GNN (clauses <-> variables), feature dim 2.
//
// Round-7 lesson: layer kernels latency/divergence-bound (VALUBusy 10%, HBM
// 1TB/s, occ 75%): per-node row loops run at the wave's MAX trip count
// (deg 0..15, mean 3) with ~1 gather in flight. Round-8: QUAD-SPLIT rows —
// 4 lanes per node (j = s+q, j += 4), 2-step __shfl_xor(width=4) reduce,
// lane-0 epilogue. Applied to c_layer and v_chunk. Build unchanged
// (two-level super-bucket partition, round-7).

#define GAB 256   // blocks for build hist/scatter passes
#define BB  1024  // threads for build hist/scatter passes

static inline int cdiv_h(long long a, long long b) { return (int)((a + b - 1) / b); }

__device__ inline float bf_lo(unsigned u) { return __uint_as_float(u << 16); }
__device__ inline float bf_hi(unsigned u) { return __uint_as_float(u & 0xffff0000u); }
__device__ inline unsigned packy(float a, float b) {
    unsigned ua = __float_as_uint(a), ub = __float_as_uint(b);
    ua = (ua + 0x7fffu + ((ua >> 16) & 1u)) >> 16;
    ub = (ub + 0x7fffu + ((ub >> 16) & 1u)) & 0xffff0000u;
    return ua | ub;
}

// ---------------- build: coarse counting partition ----------------

__global__ __launch_bounds__(BB) void hist_kernel(
    const int* __restrict__ key, int e, int chunk, int shift,
    int nb, unsigned* __restrict__ hist /*[nb][GAB]*/) {
    extern __shared__ unsigned h[];  // nb*4
    int blk = blockIdx.x, tid = threadIdx.x;
    for (int i = tid; i < nb * 4; i += blockDim.x) h[i] = 0u;
    __syncthreads();
    int s = blk * chunk, epos = min(e, s + chunk);
    int r = tid & 3;
    for (int i = s + tid; i < epos; i += blockDim.x)
        atomicAdd(&h[(((unsigned)(key[i] >> shift)) << 2) | r], 1u);
    __syncthreads();
    for (int i = tid; i < nb; i += blockDim.x)
        hist[(size_t)i * GAB + blk] = h[4 * i] + h[4 * i + 1] + h[4 * i + 2] + h[4 * i + 3];
}

__global__ void rowscan256(const unsigned* __restrict__ hist, unsigned* __restrict__ rowscan,
                           unsigned* __restrict__ row_total) {
    __shared__ unsigned ts[256];
    int b = blockIdx.x, t = threadIdx.x;
    unsigned v0 = hist[(size_t)b * GAB + t];
    ts[t] = v0;
    __syncthreads();
    for (int off = 1; off < 256; off <<= 1) {
        unsigned v = (t >= off) ? ts[t - off] : 0u;
        __syncthreads();
        ts[t] += v;
        __syncthreads();
    }
    rowscan[(size_t)b * GAB + t] = ts[t] - v0;
    if (t == 255) row_total[b] = ts[255];
}

__global__ void basescan_kernel(const unsigned* __restrict__ row_total,
                                unsigned* __restrict__ base, int nb) {
    __shared__ unsigned a[2048];
    __shared__ unsigned ts[1024];
    int t = threadIdx.x;
    a[t] = (t < nb) ? row_total[t] : 0u;
    a[t + 1024] = (t + 1024 < nb) ? row_total[t + 1024] : 0u;
    __syncthreads();
    unsigned a0 = a[2 * t], a1 = a[2 * t + 1];
    unsigned sum = a0 + a1;
    ts[t] = sum;
    __syncthreads();
    for (int off = 1; off < 1024; off <<= 1) {
        unsigned v = (t >= off) ? ts[t - off] : 0u;
        __syncthreads();
        ts[t] += v;
        __syncthreads();
    }
    unsigned b0 = ts[t] - sum;
    if (2 * t <= nb) base[2 * t] = b0;
    if (2 * t + 1 <= nb) base[2 * t + 1] = b0 + a0;
}

__global__ __launch_bounds__(BB) void scatter_sb(
    const int* __restrict__ key, const int* __restrict__ pay,
    int e, int chunk, int kshift, int nb,
    const unsigned* __restrict__ rowscan, const unsigned* __restrict__ base,
    unsigned* __restrict__ out) {
    extern __shared__ unsigned cur[];
    int blk = blockIdx.x, tid = threadIdx.x;
    for (int i = tid; i < nb; i += blockDim.x)
        cur[i] = base[i] + rowscan[(size_t)i * GAB + blk];
    __syncthreads();
    int s = blk * chunk, epos = min(e, s + chunk);
    unsigned mask = (1u << kshift) - 1u;
    for (int i = s + tid; i < epos; i += blockDim.x) {
        int k = key[i];
        int b = k >> kshift;
        unsigned p = atomicAdd(&cur[b], 1u);
        out[p] = ((unsigned)pay[i] << kshift) | ((unsigned)k & mask);
    }
}

// v-view SB localsort: block per 2048-variable super-bucket.
__global__ __launch_bounds__(1024) void localsort_v_sb(
    const unsigned* __restrict__ ent, const unsigned* __restrict__ base,
    int nsb, int nv, int cs, unsigned* __restrict__ srcs, unsigned* __restrict__ rp) {
    __shared__ unsigned h[8192];
    __shared__ unsigned ts[1024];
    int s = blockIdx.x, t = threadIdx.x;
    unsigned sb = base[s], se = base[s + 1];
    for (int k = 0; k < 8; ++k) h[t * 8 + k] = 0u;
    __syncthreads();
    for (unsigned i = sb + t; i < se; i += 1024) {
        unsigned u = ent[i];
        unsigned c = u >> 11;
        atomicAdd(&h[((u & 2047u) << 2) | (c >> cs)], 1u);
    }
    __syncthreads();
    unsigned v0[8];
    unsigned sum = 0;
    for (int k = 0; k < 8; ++k) { v0[k] = h[t * 8 + k]; sum += v0[k]; }
    ts[t] = sum;
    __syncthreads();
    for (int off = 1; off < 1024; off <<= 1) {
        unsigned x = (t >= off) ? ts[t - off] : 0u;
        __syncthreads();
        ts[t] += x;
        __syncthreads();
    }
    unsigned ex = ts[t] - sum;
    unsigned hx[8];
    for (int k = 0; k < 8; ++k) { hx[k] = ex; ex += v0[k]; }
    int node0 = s * 2048 + t * 2;
    for (int j = 0; j < 2; ++j) {
        int node = node0 + j;
        if (node < nv)
            for (int ch = 0; ch < 4; ++ch)
                rp[(size_t)node * 4 + ch] = sb + hx[j * 4 + ch];
    }
    if (s == nsb - 1 && t == 0) rp[(size_t)nv * 4] = se;
    for (int k = 0; k < 8; ++k) h[t * 8 + k] = hx[k];
    __syncthreads();
    for (unsigned i = sb + t; i < se; i += 1024) {
        unsigned u = ent[i];
        unsigned c = u >> 11;
        unsigned p = sb + atomicAdd(&h[((u & 2047u) << 2) | (c >> cs)], 1u);
        srcs[p] = c;
    }
}

// c-view SB localsort: block per 8192-clause super-bucket.
__global__ __launch_bounds__(1024) void localsort_c_sb(
    const unsigned* __restrict__ ent, const unsigned* __restrict__ base,
    int nsb, int nc, unsigned* __restrict__ srcs, unsigned* __restrict__ rp) {
    __shared__ unsigned h[8192];
    __shared__ unsigned ts[1024];
    int s = blockIdx.x, t = threadIdx.x;
    unsigned sb = base[s], se = base[s + 1];
    for (int k = 0; k < 8; ++k) h[t * 8 + k] = 0u;
    __syncthreads();
    for (unsigned i = sb + t; i < se; i += 1024)
        atomicAdd(&h[ent[i] & 8191u], 1u);
    __syncthreads();
    unsigned v0[8];
    unsigned sum = 0;
    for (int k = 0; k < 8; ++k) { v0[k] = h[t * 8 + k]; sum += v0[k]; }
    ts[t] = sum;
    __syncthreads();
    for (int off = 1; off < 1024; off <<= 1) {
        unsigned x = (t >= off) ? ts[t - off] : 0u;
        __syncthreads();
        ts[t] += x;
        __syncthreads();
    }
    unsigned ex = ts[t] - sum;
    unsigned hx[8];
    for (int k = 0; k < 8; ++k) { hx[k] = ex; ex += v0[k]; }
    int node0 = s * 8192 + t * 8;
    for (int k = 0; k < 8; ++k) {
        int node = node0 + k;
        if (node < nc) rp[node] = sb + hx[k];
    }
    if (s == nsb - 1 && t == 0) rp[nc] = se;
    for (int k = 0; k < 8; ++k) h[t * 8 + k] = hx[k];
    __syncthreads();
    for (unsigned i = sb + t; i < se; i += 1024) {
        unsigned u = ent[i];
        unsigned p = sb + atomicAdd(&h[u & 8191u], 1u);
        srcs[p] = u >> 13;
    }
}

// ---------------- node init ----------------

__global__ void init_c_kernel(const float* __restrict__ x, const float* __restrict__ deg,
                              const float* __restrict__ W0, const float* __restrict__ b0,
                              float2* __restrict__ xc, unsigned* __restrict__ yc, int n) {
    int i = blockIdx.x * blockDim.x + threadIdx.x;
    if (i >= n) return;
    float xi = x[i];
    float2 o = make_float2(fmaf(xi, W0[0], b0[0]), fmaf(xi, W0[1], b0[1]));
    xc[i] = o;
    float d = deg[i];
    float inv = (d > 0.f) ? rsqrtf(d) : 0.f;
    yc[i] = packy(inv * o.x, inv * o.y);
}

__global__ void init_v_kernel(const float* __restrict__ x, const float* __restrict__ deg,
                              const float* __restrict__ W0, const float* __restrict__ b0,
                              float2* __restrict__ xv, unsigned* __restrict__ yv, int n) {
    int i = blockIdx.x * blockDim.x + threadIdx.x;
    if (i >= n) return;
    float xi = x[i];
    float2 o = make_float2(fmaf(xi, W0[0], b0[0]), fmaf(xi, W0[1], b0[1]));
    xv[i] = o;
    float d = deg[i];
    float inv = (d > 0.f) ? rsqrtf(d) : 0.f;
    yv[i] = packy(inv * o.x, inv * o.y);
}

// ---------------- per-layer kernels (quad-split rows, no atomics) ----------------

// 4 lanes per variable node; one clause-chunk pass.
__global__ __launch_bounds__(256) void v_chunk_q(
    const unsigned* __restrict__ rp_p, const unsigned* __restrict__ src_p,
    const unsigned* __restrict__ rp_n, const unsigned* __restrict__ src_n,
    const unsigned* __restrict__ yc, float4* __restrict__ acc, int nv, int k) {
    int gt = blockIdx.x * blockDim.x + threadIdx.x;
    int i = gt >> 2, q = gt & 3;
    if (i >= nv) return;
    unsigned s0 = rp_p[(size_t)i * 4 + k], e0 = rp_p[(size_t)i * 4 + k + 1];
    unsigned s1 = rp_n[(size_t)i * 4 + k], e1 = rp_n[(size_t)i * 4 + k + 1];
    float ax = 0.f, ay = 0.f, bx = 0.f, by = 0.f;
    for (unsigned j = s0 + q; j < e0; j += 4) {
        unsigned yw = yc[src_p[j]];
        ax += bf_lo(yw); ay += bf_hi(yw);
    }
    for (unsigned j = s1 + q; j < e1; j += 4) {
        unsigned yw = yc[src_n[j]];
        bx += bf_lo(yw); by += bf_hi(yw);
    }
    for (int m = 1; m < 4; m <<= 1) {
        ax += __shfl_xor(ax, m, 4);
        ay += __shfl_xor(ay, m, 4);
        bx += __shfl_xor(bx, m, 4);
        by += __shfl_xor(by, m, 4);
    }
    if (q == 0) {
        float4 a = (k == 0) ? make_float4(0.f, 0.f, 0.f, 0.f) : acc[i];
        a.x += ax; a.y += ay; a.z += bx; a.w += by;
        acc[i] = a;
    }
}

__global__ __launch_bounds__(256) void v_finish_kernel(
    const float4* __restrict__ acc, const unsigned* __restrict__ rp_p,
    const unsigned* __restrict__ rp_n, float2* __restrict__ xv,
    const float* __restrict__ deg_v, const float* __restrict__ W,
    const float* __restrict__ bias, unsigned* __restrict__ yv_out, int nv, int writeY) {
    int i = blockIdx.x * blockDim.x + threadIdx.x;
    if (i >= nv) return;
    float4 a = acc[i];
    float cp = (float)(rp_p[(size_t)(i + 1) * 4] - rp_p[(size_t)i * 4]);
    float cn = (float)(rp_n[(size_t)(i + 1) * 4] - rp_n[(size_t)i * 4]);
    float2 xi = xv[i];
    float dv = deg_v[i];
    float iv = (dv > 0.f) ? rsqrtf(dv) : 0.f;
    float m0 = fmaf(iv, a.x, cp * xi.x);
    float m1 = fmaf(iv, a.y, cp * xi.y);
    float m2 = fmaf(iv, a.z, cn * xi.x);
    float m3 = fmaf(iv, a.w, cn * xi.y);
    float o0 = bias[0] + m0 * W[0] + m1 * W[2] + m2 * W[4] + m3 * W[6] + xi.x * W[8] + xi.y * W[10];
    float o1 = bias[1] + m0 * W[1] + m1 * W[3] + m2 * W[5] + m3 * W[7] + xi.x * W[9] + xi.y * W[11];
    xv[i] = make_float2(o0, o1);
    if (writeY) yv_out[i] = packy(iv * o0, iv * o1);
}

// 4 lanes per clause node; fused aggregation + update.
__global__ __launch_bounds__(256) void c_layer_q(
    const unsigned* __restrict__ rp_p, const unsigned* __restrict__ src_p,
    const unsigned* __restrict__ rp_n, const unsigned* __restrict__ src_n,
    const unsigned* __restrict__ yv, float2* __restrict__ xc,
    const float* __restrict__ deg_c, unsigned* __restrict__ yc,
    const float* __restrict__ W, const float* __restrict__ bias, int nc) {
    int gt = blockIdx.x * blockDim.x + threadIdx.x;
    int i = gt >> 2, q = gt & 3;
    if (i >= nc) return;
    unsigned s0 = rp_p[i], e0 = rp_p[i + 1];
    unsigned s1 = rp_n[i], e1 = rp_n[i + 1];
    float ax = 0.f, ay = 0.f, bx = 0.f, by = 0.f;
    for (unsigned j = s0 + q; j < e0; j += 4) {
        unsigned yw = yv[src_p[j]];
        ax += bf_lo(yw); ay += bf_hi(yw);
    }
    for (unsigned j = s1 + q; j < e1; j += 4) {
        unsigned yw = yv[src_n[j]];
        bx += bf_lo(yw); by += bf_hi(yw);
    }
    for (int m = 1; m < 4; m <<= 1) {
        ax += __shfl_xor(ax, m, 4);
        ay += __shfl_xor(ay, m, 4);
        bx += __shfl_xor(bx, m, 4);
        by += __shfl_xor(by, m, 4);
    }
    if (q == 0) {
        float cp = (float)(e0 - s0), cn = (float)(e1 - s1);
        float2 xi = xc[i];
        float dc = deg_c[i];
        float ic = (dc > 0.f) ? rsqrtf(dc) : 0.f;
        float m0 = fmaf(ic, ax, cp * xi.x);
        float m1 = fmaf(ic, ay, cp * xi.y);
        float m2 = fmaf(ic, bx, cn * xi.x);
        float m3 = fmaf(ic, by, cn * xi.y);
        float o0 = bias[0] + m0 * W[0] + m1 * W[2] + m2 * W[4] + m3 * W[6] + xi.x * W[8] + xi.y * W[10];
        float o1 = bias[1] + m0 * W[1] + m1 * W[3] + m2 * W[5] + m3 * W[7] + xi.x * W[9] + xi.y * W[11];
        xc[i] = make_float2(o0, o1);
        yc[i] = packy(ic * o0, ic * o1);
    }
}

// ---------------- fallback: global-atomic path ----------------

__global__ void init_nodes(const float* __restrict__ x, const float* __restrict__ deg,
                           const float* __restrict__ W0, const float* __restrict__ b0,
                           float2* __restrict__ xf, float* __restrict__ inv, int n) {
    int i = blockIdx.x * blockDim.x + threadIdx.x;
    if (i >= n) return;
    float xi = x[i];
    xf[i] = make_float2(fmaf(xi, W0[0], b0[0]), fmaf(xi, W0[1], b0[1]));
    float d = deg[i];
    inv[i] = (d > 0.0f) ? (1.0f / sqrtf(d)) : 0.0f;
}

__global__ void count_edges(const int* __restrict__ src, const int* __restrict__ trg,
                            float* __restrict__ cnt_src, float* __restrict__ cnt_trg, int e) {
    int i = blockIdx.x * blockDim.x + threadIdx.x;
    if (i >= e) return;
    atomicAdd(&cnt_src[src[i]], 1.0f);
    atomicAdd(&cnt_trg[trg[i]], 1.0f);
}

__global__ void edge_pass(const int* __restrict__ src, const int* __restrict__ trg,
                          const float2* __restrict__ xc, const float2* __restrict__ xv,
                          const float* __restrict__ inv_c, const float* __restrict__ inv_v,
                          float2* __restrict__ Sv, float2* __restrict__ Sc, int e) {
    int i = blockIdx.x * blockDim.x + threadIdx.x;
    if (i >= e) return;
    int c = src[i];
    int v = trg[i];
    float ic = inv_c[c], iv = inv_v[v];
    float2 a = xc[c];
    float2 b = xv[v];
    atomicAdd(&Sv[v].x, a.x * ic);
    atomicAdd(&Sv[v].y, a.y * ic);
    atomicAdd(&Sc[c].x, b.x * iv);
    atomicAdd(&Sc[c].y, b.y * iv);
}

__global__ void node_update(float2* __restrict__ x, const float2* __restrict__ Sp,
                            const float2* __restrict__ Sn, const float* __restrict__ inv,
                            const float* __restrict__ cp, const float* __restrict__ cn,
                            const float* __restrict__ W, const float* __restrict__ b, int n) {
    int i = blockIdx.x * blockDim.x + threadIdx.x;
    if (i >= n) return;
    float2 xi = x[i];
    float ii = inv[i];
    float2 sp = Sp[i], sn = Sn[i];
    float cpi = cp[i], cni = cn[i];
    float m0 = fmaf(ii, sp.x, cpi * xi.x);
    float m1 = fmaf(ii, sp.y, cpi * xi.y);
    float m2 = fmaf(ii, sn.x, cni * xi.x);
    float m3 = fmaf(ii, sn.y, cni * xi.y);
    float o0 = b[0] + m0 * W[0] + m1 * W[2] + m2 * W[4] + m3 * W[6] + xi.x * W[8] + xi.y * W[10];
    float o1 = b[1] + m0 * W[1] + m1 * W[3] + m2 * W[5] + m3 * W[7] + xi.x * W[9] + xi.y * W[11];
    x[i] = make_float2(o0, o1);
}

// ---------------- launch ----------------

extern "C" void kernel_launch(void* const* d_in, const int* in_sizes, int n_in,
                              void* d_out, int out_size, void* d_ws, size_t ws_size,
                              hipStream_t stream) {
    const float* x_clause   = (const float*)d_in[0];
    const float* x_variable = (const float*)d_in[1];
    const float* deg_clause = (const float*)d_in[2];
    const float* deg_var    = (const float*)d_in[3];
    const int*   pos_src    = (const int*)d_in[4];
    const int*   pos_trg    = (const int*)d_in[5];
    const int*   neg_src    = (const int*)d_in[6];
    const int*   neg_trg    = (const int*)d_in[7];
    const float* W0c        = (const float*)d_in[8];
    const float* b0c        = (const float*)d_in[9];
    const float* W0v        = (const float*)d_in[10];
    const float* b0v        = (const float*)d_in[11];
    const float* Wc         = (const float*)d_in[12];
    const float* bc         = (const float*)d_in[13];
    const float* Wv         = (const float*)d_in[14];
    const float* bv         = (const float*)d_in[15];

    const int nc = in_sizes[0];
    const int nv = in_sizes[1];
    const int e  = in_sizes[4];
    const int B = 256;

    const int NSBV = cdiv_h(nv, 2048);   // v super-buckets (2048 vars each)
    const int NSBC = cdiv_h(nc, 8192);   // c super-buckets (8192 clauses each)
    const int maxnb = NSBV > NSBC ? NSBV : NSBC;
    const bool pack_ok = (nc <= (1 << 21)) && (nv <= (1 << 19));

    int cs = 0;  // clause-chunk shift: 4 chunks cover nc
    while ((4LL << cs) < nc) cs++;

    // -------- tier-1 layout: persistent arrays + build/layer overlay --------
    {
        size_t off = 0;
        auto alloc = [&](size_t bytes) {
            void* p = (char*)d_ws + off;
            off += (bytes + 255) & ~(size_t)255;
            return p;
        };
        unsigned* srcs_vp = (unsigned*)alloc((size_t)e * 4);
        unsigned* srcs_vn = (unsigned*)alloc((size_t)e * 4);
        unsigned* srcs_cp = (unsigned*)alloc((size_t)e * 4);
        unsigned* srcs_cn = (unsigned*)alloc((size_t)e * 4);
        unsigned* rp_vp   = (unsigned*)alloc((size_t)4 * (nv + 1) * 4);  // node-major [node*4+chunk]
        unsigned* rp_vn   = (unsigned*)alloc((size_t)4 * (nv + 1) * 4);
        unsigned* rp_cp   = (unsigned*)alloc((size_t)(nc + 1) * 4);
        unsigned* rp_cn   = (unsigned*)alloc((size_t)(nc + 1) * 4);
        const size_t overlay = off;
        // build-time view
        unsigned* temp    = (unsigned*)alloc((size_t)e * 4);
        unsigned* hist    = (unsigned*)alloc((size_t)maxnb * GAB * 4);
        unsigned* rowscan = (unsigned*)alloc((size_t)maxnb * GAB * 4);
        unsigned* row_tot = (unsigned*)alloc((size_t)maxnb * 4);
        unsigned* baseb   = (unsigned*)alloc((size_t)(maxnb + 1) * 4);
        const size_t build_end = off;
        // layer-time view (overlaps build scratch; inits run AFTER build)
        off = overlay;
        float4*   accv    = (float4*)alloc((size_t)nv * 16);
        float2*   xc      = (float2*)alloc((size_t)nc * 8);
        unsigned* yc      = (unsigned*)alloc((size_t)nc * 4);
        unsigned* yv      = (unsigned*)alloc((size_t)nv * 4);
        const size_t layer_end = off;
        const size_t required = build_end > layer_end ? build_end : layer_end;

        if (required <= ws_size && pack_ok) {
            const int chunk = cdiv_h(e, GAB);
            // v-views: coarse by v>>11, SB-localsort by (v&2047)<<2|chunk(c)
            const int* vkeys[2] = { pos_trg, neg_trg };
            const int* vpays[2] = { pos_src, neg_src };
            unsigned* vsrcs[2] = { srcs_vp, srcs_vn };
            unsigned* vrps[2]  = { rp_vp, rp_vn };
            for (int p = 0; p < 2; ++p) {
                hist_kernel<<<GAB, BB, (size_t)NSBV * 16, stream>>>(vkeys[p], e, chunk, 11, NSBV, hist);
                rowscan256<<<NSBV, B, 0, stream>>>(hist, rowscan, row_tot);
                basescan_kernel<<<1, 1024, 0, stream>>>(row_tot, baseb, NSBV);
                scatter_sb<<<GAB, BB, (size_t)NSBV * 4, stream>>>(vkeys[p], vpays[p], e, chunk,
                                                                  11, NSBV, rowscan, baseb, temp);
                localsort_v_sb<<<NSBV, 1024, 0, stream>>>(temp, baseb, NSBV, nv, cs,
                                                          vsrcs[p], vrps[p]);
            }
            // c-views: coarse by c>>13, SB-localsort by c&8191
            const int* ckeys[2] = { pos_src, neg_src };
            const int* cpays[2] = { pos_trg, neg_trg };
            unsigned* csrcs[2] = { srcs_cp, srcs_cn };
            unsigned* crps[2]  = { rp_cp, rp_cn };
            for (int p = 0; p < 2; ++p) {
                hist_kernel<<<GAB, BB, (size_t)NSBC * 16, stream>>>(ckeys[p], e, chunk, 13, NSBC, hist);
                rowscan256<<<NSBC, B, 0, stream>>>(hist, rowscan, row_tot);
                basescan_kernel<<<1, 1024, 0, stream>>>(row_tot, baseb, NSBC);
                scatter_sb<<<GAB, BB, (size_t)NSBC * 4, stream>>>(ckeys[p], cpays[p], e, chunk,
                                                                  13, NSBC, rowscan, baseb, temp);
                localsort_c_sb<<<NSBC, 1024, 0, stream>>>(temp, baseb, NSBC, nc,
                                                          csrcs[p], crps[p]);
            }

            float2* xv = (float2*)d_out;  // updated in place each layer
            init_c_kernel<<<cdiv_h(nc, B), B, 0, stream>>>(x_clause, deg_clause, W0c, b0c, xc, yc, nc);
            init_v_kernel<<<cdiv_h(nv, B), B, 0, stream>>>(x_variable, deg_var, W0v, b0v, xv, yv, nv);

            for (int l = 0; l < 4; ++l) {
                for (int k = 0; k < 4; ++k) {
                    v_chunk_q<<<cdiv_h((long long)nv * 4, B), B, 0, stream>>>(
                        rp_vp, srcs_vp, rp_vn, srcs_vn, yc, accv, nv, k);
                }
                if (l < 3) {
                    c_layer_q<<<cdiv_h((long long)nc * 4, B), B, 0, stream>>>(
                        rp_cp, srcs_cp, rp_cn, srcs_cn, yv, xc, deg_clause, yc,
                        Wc + l * 12, bc + l * 2, nc);
                }
                v_finish_kernel<<<cdiv_h(nv, B), B, 0, stream>>>(accv, rp_vp, rp_vn, xv, deg_var,
                                                                 Wv + l * 12, bv + l * 2, yv, nv,
                                                                 (l < 2) ? 1 : 0);
            }
            return;
        }
    }

    // -------- fallback: global-atomic path --------
    char* p = (char*)d_ws;
    float2* Sv_pos = (float2*)p; p += (size_t)nv * sizeof(float2);
    float2* Sv_neg = (float2*)p; p += (size_t)nv * sizeof(float2);
    float2* Sc_pos = (float2*)p; p += (size_t)nc * sizeof(float2);
    float2* Sc_neg = (float2*)p; p += (size_t)nc * sizeof(float2);
    const size_t s_bytes = (size_t)(2 * nv + 2 * nc) * sizeof(float2);
    float2* xc2 = (float2*)p; p += (size_t)nc * sizeof(float2);
    float* inv_c = (float*)p; p += (size_t)nc * sizeof(float);
    float* inv_v = (float*)p; p += (size_t)nv * sizeof(float);
    float* cntc_pos = (float*)p; p += (size_t)nc * sizeof(float);
    float* cntc_neg = (float*)p; p += (size_t)nc * sizeof(float);
    float* cntv_pos = (float*)p; p += (size_t)nv * sizeof(float);
    float* cntv_neg = (float*)p; p += (size_t)nv * sizeof(float);
    const size_t cnt_bytes = (size_t)(2 * nc + 2 * nv) * sizeof(float);
    float2* xv = (float2*)d_out;

    hipMemsetAsync(Sv_pos, 0, s_bytes, stream);
    hipMemsetAsync(cntc_pos, 0, cnt_bytes, stream);
    init_nodes<<<cdiv_h(nc, B), B, 0, stream>>>(x_clause, deg_clause, W0c, b0c, xc2, inv_c, nc);
    init_nodes<<<cdiv_h(nv, B), B, 0, stream>>>(x_variable, deg_var, W0v, b0v, xv, inv_v, nv);
    count_edges<<<cdiv_h(e, B), B, 0, stream>>>(pos_src, pos_trg, cntc_pos, cntv_pos, e);
    count_edges<<<cdiv_h(e, B), B, 0, stream>>>(neg_src, neg_trg, cntc_neg, cntv_neg, e);
    for (int l = 0; l < 4; ++l) {
        edge_pass<<<cdiv_h(e, B), B, 0, stream>>>(pos_src, pos_trg, xc2, xv, inv_c, inv_v,
                                                  Sv_pos, Sc_pos, e);
        edge_pass<<<cdiv_h(e, B), B, 0, stream>>>(neg_src, neg_trg, xc2, xv, inv_c, inv_v,
                                                  Sv_neg, Sc_neg, e);
        node_update<<<cdiv_h(nv, B), B, 0, stream>>>(xv, Sv_pos, Sv_neg, inv_v,
                                                     cntv_pos, cntv_neg, Wv + l * 12, bv + l * 2, nv);
        node_update<<<cdiv_h(nc, B), B, 0, stream>>>(xc2, Sc_pos, Sc_neg, inv_c,
                                                     cntc_pos, cntc_neg, Wc + l * 12, bc + l * 2, nc);
        if (l < 3) hipMemsetAsync(Sv_pos, 0, s_bytes, stream);
    }
}

// Round 9
// 1165.131 us; speedup vs baseline: 1.6828x; 1.0038x over previous
//
#include <hip/hip_runtime.h>

// G4GCN: 4-layer linear bipartite GNN (clauses <-> variables), feature dim 2.
//
// Round-8 lesson: layer kernels limited by re-streaming CSR bytes (~190MB
// working set doesn't stay L3-resident next to 87MB inputs); quad-split fixed
// divergence but added rp/epilogue traffic (c_layer 79->88us).
// Round-9:
//  - fused pos/neg virtual row (one loop, address-select, predicated accum)
//  - v_chunk k=3 merged with the node update (v_chunk_last): no acc re-read,
//    no separate v_finish; yv ping-pong so c_layer still sees layer-l yv
//  - dead xc store skipped on last c_layer
// Build (two-level super-bucket counting sort) unchanged.

#define GAB 256   // blocks for build hist/scatter passes
#define BB  1024  // threads for build hist/scatter passes

static inline int cdiv_h(long long a, long long b) { return (int)((a + b - 1) / b); }

__device__ inline float bf_lo(unsigned u) { return __uint_as_float(u << 16); }
__device__ inline float bf_hi(unsigned u) { return __uint_as_float(u & 0xffff0000u); }
__device__ inline unsigned packy(float a, float b) {
    unsigned ua = __float_as_uint(a), ub = __float_as_uint(b);
    ua = (ua + 0x7fffu + ((ua >> 16) & 1u)) >> 16;
    ub = (ub + 0x7fffu + ((ub >> 16) & 1u)) & 0xffff0000u;
    return ua | ub;
}

// ---------------- build: coarse counting partition ----------------

__global__ __launch_bounds__(BB) void hist_kernel(
    const int* __restrict__ key, int e, int chunk, int shift,
    int nb, unsigned* __restrict__ hist /*[nb][GAB]*/) {
    extern __shared__ unsigned h[];  // nb*4
    int blk = blockIdx.x, tid = threadIdx.x;
    for (int i = tid; i < nb * 4; i += blockDim.x) h[i] = 0u;
    __syncthreads();
    int s = blk * chunk, epos = min(e, s + chunk);
    int r = tid & 3;
    for (int i = s + tid; i < epos; i += blockDim.x)
        atomicAdd(&h[(((unsigned)(key[i] >> shift)) << 2) | r], 1u);
    __syncthreads();
    for (int i = tid; i < nb; i += blockDim.x)
        hist[(size_t)i * GAB + blk] = h[4 * i] + h[4 * i + 1] + h[4 * i + 2] + h[4 * i + 3];
}

__global__ void rowscan256(const unsigned* __restrict__ hist, unsigned* __restrict__ rowscan,
                           unsigned* __restrict__ row_total) {
    __shared__ unsigned ts[256];
    int b = blockIdx.x, t = threadIdx.x;
    unsigned v0 = hist[(size_t)b * GAB + t];
    ts[t] = v0;
    __syncthreads();
    for (int off = 1; off < 256; off <<= 1) {
        unsigned v = (t >= off) ? ts[t - off] : 0u;
        __syncthreads();
        ts[t] += v;
        __syncthreads();
    }
    rowscan[(size_t)b * GAB + t] = ts[t] - v0;
    if (t == 255) row_total[b] = ts[255];
}

__global__ void basescan_kernel(const unsigned* __restrict__ row_total,
                                unsigned* __restrict__ base, int nb) {
    __shared__ unsigned a[2048];
    __shared__ unsigned ts[1024];
    int t = threadIdx.x;
    a[t] = (t < nb) ? row_total[t] : 0u;
    a[t + 1024] = (t + 1024 < nb) ? row_total[t + 1024] : 0u;
    __syncthreads();
    unsigned a0 = a[2 * t], a1 = a[2 * t + 1];
    unsigned sum = a0 + a1;
    ts[t] = sum;
    __syncthreads();
    for (int off = 1; off < 1024; off <<= 1) {
        unsigned v = (t >= off) ? ts[t - off] : 0u;
        __syncthreads();
        ts[t] += v;
        __syncthreads();
    }
    unsigned b0 = ts[t] - sum;
    if (2 * t <= nb) base[2 * t] = b0;
    if (2 * t + 1 <= nb) base[2 * t + 1] = b0 + a0;
}

__global__ __launch_bounds__(BB) void scatter_sb(
    const int* __restrict__ key, const int* __restrict__ pay,
    int e, int chunk, int kshift, int nb,
    const unsigned* __restrict__ rowscan, const unsigned* __restrict__ base,
    unsigned* __restrict__ out) {
    extern __shared__ unsigned cur[];
    int blk = blockIdx.x, tid = threadIdx.x;
    for (int i = tid; i < nb; i += blockDim.x)
        cur[i] = base[i] + rowscan[(size_t)i * GAB + blk];
    __syncthreads();
    int s = blk * chunk, epos = min(e, s + chunk);
    unsigned mask = (1u << kshift) - 1u;
    for (int i = s + tid; i < epos; i += blockDim.x) {
        int k = key[i];
        int b = k >> kshift;
        unsigned p = atomicAdd(&cur[b], 1u);
        out[p] = ((unsigned)pay[i] << kshift) | ((unsigned)k & mask);
    }
}

// v-view SB localsort: block per 2048-variable super-bucket.
__global__ __launch_bounds__(1024) void localsort_v_sb(
    const unsigned* __restrict__ ent, const unsigned* __restrict__ base,
    int nsb, int nv, int cs, unsigned* __restrict__ srcs, unsigned* __restrict__ rp) {
    __shared__ unsigned h[8192];
    __shared__ unsigned ts[1024];
    int s = blockIdx.x, t = threadIdx.x;
    unsigned sb = base[s], se = base[s + 1];
    for (int k = 0; k < 8; ++k) h[t * 8 + k] = 0u;
    __syncthreads();
    for (unsigned i = sb + t; i < se; i += 1024) {
        unsigned u = ent[i];
        unsigned c = u >> 11;
        atomicAdd(&h[((u & 2047u) << 2) | (c >> cs)], 1u);
    }
    __syncthreads();
    unsigned v0[8];
    unsigned sum = 0;
    for (int k = 0; k < 8; ++k) { v0[k] = h[t * 8 + k]; sum += v0[k]; }
    ts[t] = sum;
    __syncthreads();
    for (int off = 1; off < 1024; off <<= 1) {
        unsigned x = (t >= off) ? ts[t - off] : 0u;
        __syncthreads();
        ts[t] += x;
        __syncthreads();
    }
    unsigned ex = ts[t] - sum;
    unsigned hx[8];
    for (int k = 0; k < 8; ++k) { hx[k] = ex; ex += v0[k]; }
    int node0 = s * 2048 + t * 2;
    for (int j = 0; j < 2; ++j) {
        int node = node0 + j;
        if (node < nv)
            for (int ch = 0; ch < 4; ++ch)
                rp[(size_t)node * 4 + ch] = sb + hx[j * 4 + ch];
    }
    if (s == nsb - 1 && t == 0) rp[(size_t)nv * 4] = se;
    for (int k = 0; k < 8; ++k) h[t * 8 + k] = hx[k];
    __syncthreads();
    for (unsigned i = sb + t; i < se; i += 1024) {
        unsigned u = ent[i];
        unsigned c = u >> 11;
        unsigned p = sb + atomicAdd(&h[((u & 2047u) << 2) | (c >> cs)], 1u);
        srcs[p] = c;
    }
}

// c-view SB localsort: block per 8192-clause super-bucket.
__global__ __launch_bounds__(1024) void localsort_c_sb(
    const unsigned* __restrict__ ent, const unsigned* __restrict__ base,
    int nsb, int nc, unsigned* __restrict__ srcs, unsigned* __restrict__ rp) {
    __shared__ unsigned h[8192];
    __shared__ unsigned ts[1024];
    int s = blockIdx.x, t = threadIdx.x;
    unsigned sb = base[s], se = base[s + 1];
    for (int k = 0; k < 8; ++k) h[t * 8 + k] = 0u;
    __syncthreads();
    for (unsigned i = sb + t; i < se; i += 1024)
        atomicAdd(&h[ent[i] & 8191u], 1u);
    __syncthreads();
    unsigned v0[8];
    unsigned sum = 0;
    for (int k = 0; k < 8; ++k) { v0[k] = h[t * 8 + k]; sum += v0[k]; }
    ts[t] = sum;
    __syncthreads();
    for (int off = 1; off < 1024; off <<= 1) {
        unsigned x = (t >= off) ? ts[t - off] : 0u;
        __syncthreads();
        ts[t] += x;
        __syncthreads();
    }
    unsigned ex = ts[t] - sum;
    unsigned hx[8];
    for (int k = 0; k < 8; ++k) { hx[k] = ex; ex += v0[k]; }
    int node0 = s * 8192 + t * 8;
    for (int k = 0; k < 8; ++k) {
        int node = node0 + k;
        if (node < nc) rp[node] = sb + hx[k];
    }
    if (s == nsb - 1 && t == 0) rp[nc] = se;
    for (int k = 0; k < 8; ++k) h[t * 8 + k] = hx[k];
    __syncthreads();
    for (unsigned i = sb + t; i < se; i += 1024) {
        unsigned u = ent[i];
        unsigned p = sb + atomicAdd(&h[u & 8191u], 1u);
        srcs[p] = u >> 13;
    }
}

// ---------------- node init ----------------

__global__ void init_c_kernel(const float* __restrict__ x, const float* __restrict__ deg,
                              const float* __restrict__ W0, const float* __restrict__ b0,
                              float2* __restrict__ xc, unsigned* __restrict__ yc, int n) {
    int i = blockIdx.x * blockDim.x + threadIdx.x;
    if (i >= n) return;
    float xi = x[i];
    float2 o = make_float2(fmaf(xi, W0[0], b0[0]), fmaf(xi, W0[1], b0[1]));
    xc[i] = o;
    float d = deg[i];
    float inv = (d > 0.f) ? rsqrtf(d) : 0.f;
    yc[i] = packy(inv * o.x, inv * o.y);
}

__global__ void init_v_kernel(const float* __restrict__ x, const float* __restrict__ deg,
                              const float* __restrict__ W0, const float* __restrict__ b0,
                              float2* __restrict__ xv, unsigned* __restrict__ yv, int n) {
    int i = blockIdx.x * blockDim.x + threadIdx.x;
    if (i >= n) return;
    float xi = x[i];
    float2 o = make_float2(fmaf(xi, W0[0], b0[0]), fmaf(xi, W0[1], b0[1]));
    xv[i] = o;
    float d = deg[i];
    float inv = (d > 0.f) ? rsqrtf(d) : 0.f;
    yv[i] = packy(inv * o.x, inv * o.y);
}

// ---------------- per-layer kernels (quad-split, fused pos/neg row) ----------------

// chunks k = 0..2: accumulate into acc (float4: pos.xy, neg.zw).
__global__ __launch_bounds__(256) void v_chunk_q(
    const unsigned* __restrict__ rp_p, const unsigned* __restrict__ src_p,
    const unsigned* __restrict__ rp_n, const unsigned* __restrict__ src_n,
    const unsigned* __restrict__ yc, float4* __restrict__ acc, int nv, int k) {
    int gt = blockIdx.x * blockDim.x + threadIdx.x;
    int i = gt >> 2, q = gt & 3;
    if (i >= nv) return;
    unsigned s0 = rp_p[(size_t)i * 4 + k], e0 = rp_p[(size_t)i * 4 + k + 1];
    unsigned s1 = rp_n[(size_t)i * 4 + k], e1 = rp_n[(size_t)i * 4 + k + 1];
    unsigned dp = e0 - s0, d = dp + (e1 - s1);
    float ax = 0.f, ay = 0.f, bx = 0.f, by = 0.f;
    for (unsigned j = q; j < d; j += 4) {
        bool isp = j < dp;
        const unsigned* sp = isp ? (src_p + s0 + j) : (src_n + s1 + (j - dp));
        unsigned yw = yc[*sp];
        float lo = bf_lo(yw), hi = bf_hi(yw);
        float tp = isp ? 1.0f : 0.0f;
        ax = fmaf(tp, lo, ax); ay = fmaf(tp, hi, ay);
        bx = fmaf(1.0f - tp, lo, bx); by = fmaf(1.0f - tp, hi, by);
    }
    for (int m = 1; m < 4; m <<= 1) {
        ax += __shfl_xor(ax, m, 4);
        ay += __shfl_xor(ay, m, 4);
        bx += __shfl_xor(bx, m, 4);
        by += __shfl_xor(by, m, 4);
    }
    if (q == 0) {
        float4 a = (k == 0) ? make_float4(0.f, 0.f, 0.f, 0.f) : acc[i];
        a.x += ax; a.y += ay; a.z += bx; a.w += by;
        acc[i] = a;
    }
}

// chunk k = 3 fused with the node update: lane 0 applies the 6->2 layer.
__global__ __launch_bounds__(256) void v_chunk_last(
    const unsigned* __restrict__ rp_p, const unsigned* __restrict__ src_p,
    const unsigned* __restrict__ rp_n, const unsigned* __restrict__ src_n,
    const unsigned* __restrict__ yc, const float4* __restrict__ acc,
    float2* __restrict__ xv, const float* __restrict__ deg_v,
    const float* __restrict__ W, const float* __restrict__ bias,
    unsigned* __restrict__ yv_out, int nv, int writeY) {
    int gt = blockIdx.x * blockDim.x + threadIdx.x;
    int i = gt >> 2, q = gt & 3;
    if (i >= nv) return;
    uint4 rpp = *reinterpret_cast<const uint4*>(rp_p + (size_t)i * 4);  // row start, ., ., k3 start
    uint4 rpn = *reinterpret_cast<const uint4*>(rp_n + (size_t)i * 4);
    unsigned e0 = rp_p[(size_t)(i + 1) * 4];  // row end = next row start
    unsigned e1 = rp_n[(size_t)(i + 1) * 4];
    unsigned s0 = rpp.w, s1 = rpn.w;
    unsigned dp = e0 - s0, d = dp + (e1 - s1);
    float ax = 0.f, ay = 0.f, bx = 0.f, by = 0.f;
    for (unsigned j = q; j < d; j += 4) {
        bool isp = j < dp;
        const unsigned* sp = isp ? (src_p + s0 + j) : (src_n + s1 + (j - dp));
        unsigned yw = yc[*sp];
        float lo = bf_lo(yw), hi = bf_hi(yw);
        float tp = isp ? 1.0f : 0.0f;
        ax = fmaf(tp, lo, ax); ay = fmaf(tp, hi, ay);
        bx = fmaf(1.0f - tp, lo, bx); by = fmaf(1.0f - tp, hi, by);
    }
    for (int m = 1; m < 4; m <<= 1) {
        ax += __shfl_xor(ax, m, 4);
        ay += __shfl_xor(ay, m, 4);
        bx += __shfl_xor(bx, m, 4);
        by += __shfl_xor(by, m, 4);
    }
    if (q == 0) {
        float4 a = acc[i];
        a.x += ax; a.y += ay; a.z += bx; a.w += by;
        float cp = (float)(e0 - rpp.x);
        float cn = (float)(e1 - rpn.x);
        float2 xi = xv[i];
        float dv = deg_v[i];
        float iv = (dv > 0.f) ? rsqrtf(dv) : 0.f;
        float m0 = fmaf(iv, a.x, cp * xi.x);
        float m1 = fmaf(iv, a.y, cp * xi.y);
        float m2 = fmaf(iv, a.z, cn * xi.x);
        float m3 = fmaf(iv, a.w, cn * xi.y);
        float o0 = bias[0] + m0 * W[0] + m1 * W[2] + m2 * W[4] + m3 * W[6] + xi.x * W[8] + xi.y * W[10];
        float o1 = bias[1] + m0 * W[1] + m1 * W[3] + m2 * W[5] + m3 * W[7] + xi.x * W[9] + xi.y * W[11];
        xv[i] = make_float2(o0, o1);
        if (writeY) yv_out[i] = packy(iv * o0, iv * o1);
    }
}

// clause layer: fused pos/neg row; optional xc store (dead on last use).
__global__ __launch_bounds__(256) void c_layer_q(
    const unsigned* __restrict__ rp_p, const unsigned* __restrict__ src_p,
    const unsigned* __restrict__ rp_n, const unsigned* __restrict__ src_n,
    const unsigned* __restrict__ yv, float2* __restrict__ xc,
    const float* __restrict__ deg_c, unsigned* __restrict__ yc,
    const float* __restrict__ W, const float* __restrict__ bias, int nc, int writeX) {
    int gt = blockIdx.x * blockDim.x + threadIdx.x;
    int i = gt >> 2, q = gt & 3;
    if (i >= nc) return;
    unsigned s0 = rp_p[i], e0 = rp_p[i + 1];
    unsigned s1 = rp_n[i], e1 = rp_n[i + 1];
    unsigned dp = e0 - s0, d = dp + (e1 - s1);
    float ax = 0.f, ay = 0.f, bx = 0.f, by = 0.f;
    for (unsigned j = q; j < d; j += 4) {
        bool isp = j < dp;
        const unsigned* sp = isp ? (src_p + s0 + j) : (src_n + s1 + (j - dp));
        unsigned yw = yv[*sp];
        float lo = bf_lo(yw), hi = bf_hi(yw);
        float tp = isp ? 1.0f : 0.0f;
        ax = fmaf(tp, lo, ax); ay = fmaf(tp, hi, ay);
        bx = fmaf(1.0f - tp, lo, bx); by = fmaf(1.0f - tp, hi, by);
    }
    for (int m = 1; m < 4; m <<= 1) {
        ax += __shfl_xor(ax, m, 4);
        ay += __shfl_xor(ay, m, 4);
        bx += __shfl_xor(bx, m, 4);
        by += __shfl_xor(by, m, 4);
    }
    if (q == 0) {
        float cp = (float)dp, cn = (float)(e1 - s1);
        float2 xi = xc[i];
        float dc = deg_c[i];
        float ic = (dc > 0.f) ? rsqrtf(dc) : 0.f;
        float m0 = fmaf(ic, ax, cp * xi.x);
        float m1 = fmaf(ic, ay, cp * xi.y);
        float m2 = fmaf(ic, bx, cn * xi.x);
        float m3 = fmaf(ic, by, cn * xi.y);
        float o0 = bias[0] + m0 * W[0] + m1 * W[2] + m2 * W[4] + m3 * W[6] + xi.x * W[8] + xi.y * W[10];
        float o1 = bias[1] + m0 * W[1] + m1 * W[3] + m2 * W[5] + m3 * W[7] + xi.x * W[9] + xi.y * W[11];
        if (writeX) xc[i] = make_float2(o0, o1);
        yc[i] = packy(ic * o0, ic * o1);
    }
}

// ---------------- fallback: global-atomic path ----------------

__global__ void init_nodes(const float* __restrict__ x, const float* __restrict__ deg,
                           const float* __restrict__ W0, const float* __restrict__ b0,
                           float2* __restrict__ xf, float* __restrict__ inv, int n) {
    int i = blockIdx.x * blockDim.x + threadIdx.x;
    if (i >= n) return;
    float xi = x[i];
    xf[i] = make_float2(fmaf(xi, W0[0], b0[0]), fmaf(xi, W0[1], b0[1]));
    float d = deg[i];
    inv[i] = (d > 0.0f) ? (1.0f / sqrtf(d)) : 0.0f;
}

__global__ void count_edges(const int* __restrict__ src, const int* __restrict__ trg,
                            float* __restrict__ cnt_src, float* __restrict__ cnt_trg, int e) {
    int i = blockIdx.x * blockDim.x + threadIdx.x;
    if (i >= e) return;
    atomicAdd(&cnt_src[src[i]], 1.0f);
    atomicAdd(&cnt_trg[trg[i]], 1.0f);
}

__global__ void edge_pass(const int* __restrict__ src, const int* __restrict__ trg,
                          const float2* __restrict__ xc, const float2* __restrict__ xv,
                          const float* __restrict__ inv_c, const float* __restrict__ inv_v,
                          float2* __restrict__ Sv, float2* __restrict__ Sc, int e) {
    int i = blockIdx.x * blockDim.x + threadIdx.x;
    if (i >= e) return;
    int c = src[i];
    int v = trg[i];
    float ic = inv_c[c], iv = inv_v[v];
    float2 a = xc[c];
    float2 b = xv[v];
    atomicAdd(&Sv[v].x, a.x * ic);
    atomicAdd(&Sv[v].y, a.y * ic);
    atomicAdd(&Sc[c].x, b.x * iv);
    atomicAdd(&Sc[c].y, b.y * iv);
}

__global__ void node_update(float2* __restrict__ x, const float2* __restrict__ Sp,
                            const float2* __restrict__ Sn, const float* __restrict__ inv,
                            const float* __restrict__ cp, const float* __restrict__ cn,
                            const float* __restrict__ W, const float* __restrict__ b, int n) {
    int i = blockIdx.x * blockDim.x + threadIdx.x;
    if (i >= n) return;
    float2 xi = x[i];
    float ii = inv[i];
    float2 sp = Sp[i], sn = Sn[i];
    float cpi = cp[i], cni = cn[i];
    float m0 = fmaf(ii, sp.x, cpi * xi.x);
    float m1 = fmaf(ii, sp.y, cpi * xi.y);
    float m2 = fmaf(ii, sn.x, cni * xi.x);
    float m3 = fmaf(ii, sn.y, cni * xi.y);
    float o0 = b[0] + m0 * W[0] + m1 * W[2] + m2 * W[4] + m3 * W[6] + xi.x * W[8] + xi.y * W[10];
    float o1 = b[1] + m0 * W[1] + m1 * W[3] + m2 * W[5] + m3 * W[7] + xi.x * W[9] + xi.y * W[11];
    x[i] = make_float2(o0, o1);
}

// ---------------- launch ----------------

extern "C" void kernel_launch(void* const* d_in, const int* in_sizes, int n_in,
                              void* d_out, int out_size, void* d_ws, size_t ws_size,
                              hipStream_t stream) {
    const float* x_clause   = (const float*)d_in[0];
    const float* x_variable = (const float*)d_in[1];
    const float* deg_clause = (const float*)d_in[2];
    const float* deg_var    = (const float*)d_in[3];
    const int*   pos_src    = (const int*)d_in[4];
    const int*   pos_trg    = (const int*)d_in[5];
    const int*   neg_src    = (const int*)d_in[6];
    const int*   neg_trg    = (const int*)d_in[7];
    const float* W0c        = (const float*)d_in[8];
    const float* b0c        = (const float*)d_in[9];
    const float* W0v        = (const float*)d_in[10];
    const float* b0v        = (const float*)d_in[11];
    const float* Wc         = (const float*)d_in[12];
    const float* bc         = (const float*)d_in[13];
    const float* Wv         = (const float*)d_in[14];
    const float* bv         = (const float*)d_in[15];

    const int nc = in_sizes[0];
    const int nv = in_sizes[1];
    const int e  = in_sizes[4];
    const int B = 256;

    const int NSBV = cdiv_h(nv, 2048);   // v super-buckets (2048 vars each)
    const int NSBC = cdiv_h(nc, 8192);   // c super-buckets (8192 clauses each)
    const int maxnb = NSBV > NSBC ? NSBV : NSBC;
    const bool pack_ok = (nc <= (1 << 21)) && (nv <= (1 << 19));

    int cs = 0;  // clause-chunk shift: 4 chunks cover nc
    while ((4LL << cs) < nc) cs++;

    // -------- tier-1 layout: persistent arrays + build/layer overlay --------
    {
        size_t off = 0;
        auto alloc = [&](size_t bytes) {
            void* p = (char*)d_ws + off;
            off += (bytes + 255) & ~(size_t)255;
            return p;
        };
        unsigned* srcs_vp = (unsigned*)alloc((size_t)e * 4);
        unsigned* srcs_vn = (unsigned*)alloc((size_t)e * 4);
        unsigned* srcs_cp = (unsigned*)alloc((size_t)e * 4);
        unsigned* srcs_cn = (unsigned*)alloc((size_t)e * 4);
        unsigned* rp_vp   = (unsigned*)alloc((size_t)4 * (nv + 1) * 4);  // node-major [node*4+chunk]
        unsigned* rp_vn   = (unsigned*)alloc((size_t)4 * (nv + 1) * 4);
        unsigned* rp_cp   = (unsigned*)alloc((size_t)(nc + 1) * 4);
        unsigned* rp_cn   = (unsigned*)alloc((size_t)(nc + 1) * 4);
        const size_t overlay = off;
        // build-time view
        unsigned* temp    = (unsigned*)alloc((size_t)e * 4);
        unsigned* hist    = (unsigned*)alloc((size_t)maxnb * GAB * 4);
        unsigned* rowscan = (unsigned*)alloc((size_t)maxnb * GAB * 4);
        unsigned* row_tot = (unsigned*)alloc((size_t)maxnb * 4);
        unsigned* baseb   = (unsigned*)alloc((size_t)(maxnb + 1) * 4);
        const size_t build_end = off;
        // layer-time view (overlaps build scratch; inits run AFTER build)
        off = overlay;
        float4*   accv    = (float4*)alloc((size_t)nv * 16);
        float2*   xc      = (float2*)alloc((size_t)nc * 8);
        unsigned* yc      = (unsigned*)alloc((size_t)nc * 4);
        unsigned* yvA     = (unsigned*)alloc((size_t)nv * 4);
        unsigned* yvB     = (unsigned*)alloc((size_t)nv * 4);
        const size_t layer_end = off;
        const size_t required = build_end > layer_end ? build_end : layer_end;

        if (required <= ws_size && pack_ok) {
            const int chunk = cdiv_h(e, GAB);
            // v-views: coarse by v>>11, SB-localsort by (v&2047)<<2|chunk(c)
            const int* vkeys[2] = { pos_trg, neg_trg };
            const int* vpays[2] = { pos_src, neg_src };
            unsigned* vsrcs[2] = { srcs_vp, srcs_vn };
            unsigned* vrps[2]  = { rp_vp, rp_vn };
            for (int p = 0; p < 2; ++p) {
                hist_kernel<<<GAB, BB, (size_t)NSBV * 16, stream>>>(vkeys[p], e, chunk, 11, NSBV, hist);
                rowscan256<<<NSBV, B, 0, stream>>>(hist, rowscan, row_tot);
                basescan_kernel<<<1, 1024, 0, stream>>>(row_tot, baseb, NSBV);
                scatter_sb<<<GAB, BB, (size_t)NSBV * 4, stream>>>(vkeys[p], vpays[p], e, chunk,
                                                                  11, NSBV, rowscan, baseb, temp);
                localsort_v_sb<<<NSBV, 1024, 0, stream>>>(temp, baseb, NSBV, nv, cs,
                                                          vsrcs[p], vrps[p]);
            }
            // c-views: coarse by c>>13, SB-localsort by c&8191
            const int* ckeys[2] = { pos_src, neg_src };
            const int* cpays[2] = { pos_trg, neg_trg };
            unsigned* csrcs[2] = { srcs_cp, srcs_cn };
            unsigned* crps[2]  = { rp_cp, rp_cn };
            for (int p = 0; p < 2; ++p) {
                hist_kernel<<<GAB, BB, (size_t)NSBC * 16, stream>>>(ckeys[p], e, chunk, 13, NSBC, hist);
                rowscan256<<<NSBC, B, 0, stream>>>(hist, rowscan, row_tot);
                basescan_kernel<<<1, 1024, 0, stream>>>(row_tot, baseb, NSBC);
                scatter_sb<<<GAB, BB, (size_t)NSBC * 4, stream>>>(ckeys[p], cpays[p], e, chunk,
                                                                  13, NSBC, rowscan, baseb, temp);
                localsort_c_sb<<<NSBC, 1024, 0, stream>>>(temp, baseb, NSBC, nc,
                                                          csrcs[p], crps[p]);
            }

            float2* xv = (float2*)d_out;  // updated in place each layer
            init_c_kernel<<<cdiv_h(nc, B), B, 0, stream>>>(x_clause, deg_clause, W0c, b0c, xc, yc, nc);
            init_v_kernel<<<cdiv_h(nv, B), B, 0, stream>>>(x_variable, deg_var, W0v, b0v, xv, yvA, nv);

            unsigned* ycur = yvA;  // yv of layer l
            unsigned* ynxt = yvB;  // yv of layer l+1 (written by v_chunk_last)
            for (int l = 0; l < 4; ++l) {
                for (int k = 0; k < 3; ++k) {
                    v_chunk_q<<<cdiv_h((long long)nv * 4, B), B, 0, stream>>>(
                        rp_vp, srcs_vp, rp_vn, srcs_vn, yc, accv, nv, k);
                }
                // chunk 3 + node update; writes xv in place and yv_{l+1} into ynxt
                v_chunk_last<<<cdiv_h((long long)nv * 4, B), B, 0, stream>>>(
                    rp_vp, srcs_vp, rp_vn, srcs_vn, yc, accv, xv, deg_var,
                    Wv + l * 12, bv + l * 2, ynxt, nv, (l < 2) ? 1 : 0);
                if (l < 3) {
                    // reads yv_l (ycur, untouched), writes yc_{l+1} (+ xc unless dead)
                    c_layer_q<<<cdiv_h((long long)nc * 4, B), B, 0, stream>>>(
                        rp_cp, srcs_cp, rp_cn, srcs_cn, ycur, xc, deg_clause, yc,
                        Wc + l * 12, bc + l * 2, nc, (l < 2) ? 1 : 0);
                }
                unsigned* ty = ycur; ycur = ynxt; ynxt = ty;
            }
            return;
        }
    }

    // -------- fallback: global-atomic path --------
    char* p = (char*)d_ws;
    float2* Sv_pos = (float2*)p; p += (size_t)nv * sizeof(float2);
    float2* Sv_neg = (float2*)p; p += (size_t)nv * sizeof(float2);
    float2* Sc_pos = (float2*)p; p += (size_t)nc * sizeof(float2);
    float2* Sc_neg = (float2*)p; p += (size_t)nc * sizeof(float2);
    const size_t s_bytes = (size_t)(2 * nv + 2 * nc) * sizeof(float2);
    float2* xc2 = (float2*)p; p += (size_t)nc * sizeof(float2);
    float* inv_c = (float*)p; p += (size_t)nc * sizeof(float);
    float* inv_v = (float*)p; p += (size_t)nv * sizeof(float);
    float* cntc_pos = (float*)p; p += (size_t)nc * sizeof(float);
    float* cntc_neg = (float*)p; p += (size_t)nc * sizeof(float);
    float* cntv_pos = (float*)p; p += (size_t)nv * sizeof(float);
    float* cntv_neg = (float*)p; p += (size_t)nv * sizeof(float);
    const size_t cnt_bytes = (size_t)(2 * nc + 2 * nv) * sizeof(float);
    float2* xv = (float2*)d_out;

    hipMemsetAsync(Sv_pos, 0, s_bytes, stream);
    hipMemsetAsync(cntc_pos, 0, cnt_bytes, stream);
    init_nodes<<<cdiv_h(nc, B), B, 0, stream>>>(x_clause, deg_clause, W0c, b0c, xc2, inv_c, nc);
    init_nodes<<<cdiv_h(nv, B), B, 0, stream>>>(x_variable, deg_var, W0v, b0v, xv, inv_v, nv);
    count_edges<<<cdiv_h(e, B), B, 0, stream>>>(pos_src, pos_trg, cntc_pos, cntv_pos, e);
    count_edges<<<cdiv_h(e, B), B, 0, stream>>>(neg_src, neg_trg, cntc_neg, cntv_neg, e);
    for (int l = 0; l < 4; ++l) {
        edge_pass<<<cdiv_h(e, B), B, 0, stream>>>(pos_src, pos_trg, xc2, xv, inv_c, inv_v,
                                                  Sv_pos, Sc_pos, e);
        edge_pass<<<cdiv_h(e, B), B, 0, stream>>>(neg_src, neg_trg, xc2, xv, inv_c, inv_v,
                                                  Sv_neg, Sc_neg, e);
        node_update<<<cdiv_h(nv, B), B, 0, stream>>>(xv, Sv_pos, Sv_neg, inv_v,
                                                     cntv_pos, cntv_neg, Wv + l * 12, bv + l * 2, nv);
        node_update<<<cdiv_h(nc, B), B, 0, stream>>>(xc2, Sc_pos, Sc_neg, inv_c,
                                                     cntc_pos, cntc_neg, Wc + l * 12, bc + l * 2, nc);
        if (l < 3) hipMemsetAsync(Sv_pos, 0, s_bytes, stream);
    }
}